// Round 1
// 1376.459 us; speedup vs baseline: 1.2278x; 1.2278x over previous
//
#include <hip/hip_runtime.h>
#include <math.h>

#define BB 64
#define CC 768
#define NN 1024
#define BS 192
#define EPS 1e-5f
#define LAM 0.01f

typedef float  f32x4  __attribute__((ext_vector_type(4)));
typedef short  bf16x8 __attribute__((ext_vector_type(8)));

__device__ inline unsigned f2bf(float x) {
    unsigned u = __float_as_uint(x);
    u += 0x7fff + ((u >> 16) & 1);   // RNE
    return u >> 16;
}
__device__ inline unsigned pack2(float r, float i) { return f2bf(r) | (f2bf(i) << 16); }
__device__ inline float bflo(unsigned v) { return __uint_as_float(v << 16); }
__device__ inline float bfhi(unsigned v) { return __uint_as_float(v & 0xffff0000u); }

// ---------------------------------------------------------------------------
// Kernel 1: LayerNorm statistics per (b, n).
// ---------------------------------------------------------------------------
__global__ void ln_stats(const float* __restrict__ x,
                         float* __restrict__ mu, float* __restrict__ rstd) {
    int tn = threadIdx.x & 63, tc = threadIdx.x >> 6;
    int n = blockIdx.x * 64 + tn, b = blockIdx.y;
    const float* xp = x + (size_t)b * CC * NN + n;
    float s = 0.f, ss = 0.f;
    for (int c = tc; c < CC; c += 4) {
        float v = xp[(size_t)c * NN];
        s += v; ss += v * v;
    }
    __shared__ float sm[4][64], sq[4][64];
    sm[tc][tn] = s; sq[tc][tn] = ss;
    __syncthreads();
    if (tc == 0) {
        s  = sm[0][tn] + sm[1][tn] + sm[2][tn] + sm[3][tn];
        ss = sq[0][tn] + sq[1][tn] + sq[2][tn] + sq[3][tn];
        float m = s * (1.f / 768.f);
        float v = ss * (1.f / 768.f) - m * m;
        mu[b * NN + n] = m;
        rstd[b * NN + n] = rsqrtf(v + EPS);
    }
}

// ---------------------------------------------------------------------------
// Kernel 2: LN-apply + 1024-pt DIF FFT (n) + 4-pt DFT (q) + 1/64 scale.
// Output: packed bf16 complex planes Xp[(b*4+q)*192 + d][n], dword=(re|im<<16).
// n is bit-reversed (MLP is n-order agnostic; inverse undoes it).
// ---------------------------------------------------------------------------
__global__ void fwd_fft(const float* __restrict__ x,
                        const float* __restrict__ mu_, const float* __restrict__ rs_,
                        const float* __restrict__ gamma, const float* __restrict__ beta,
                        unsigned* __restrict__ Xp) {
    __shared__ float re[4][1024], im[4][1024];
    int d = blockIdx.x, b = blockIdx.y, tid = threadIdx.x;

    const float* mp = mu_ + b * NN;
    const float* rp = rs_ + b * NN;
    for (int q = 0; q < 4; q++) {
        int c = q * BS + d;
        float g = gamma[c], be = beta[c];
        const float* xp = x + ((size_t)b * CC + c) * NN;
        for (int n = tid; n < NN; n += 256) {
            re[q][n] = (xp[n] - mp[n]) * rp[n] * g + be;
            im[q][n] = 0.f;
        }
    }
    __syncthreads();

    for (int len = 512; len >= 1; len >>= 1) {
        for (int t = tid; t < 512; t += 256) {
            int j = t & (len - 1);
            int i0 = ((t - j) << 1) + j;
            int i1 = i0 + len;
            float ang = -(float)M_PI * (float)j / (float)len;
            float sw, cw;
            __sincosf(ang, &sw, &cw);
            #pragma unroll
            for (int q = 0; q < 4; q++) {
                float ar = re[q][i0], ai = im[q][i0];
                float br = re[q][i1], bi = im[q][i1];
                re[q][i0] = ar + br; im[q][i0] = ai + bi;
                float dr = ar - br, di = ai - bi;
                re[q][i1] = dr * cw - di * sw;
                im[q][i1] = dr * sw + di * cw;
            }
        }
        __syncthreads();
    }

    const float sc = 1.f / 64.f;
    for (int n = tid; n < NN; n += 256) {
        float x0r = re[0][n], x0i = im[0][n];
        float x1r = re[1][n], x1i = im[1][n];
        float x2r = re[2][n], x2i = im[2][n];
        float x3r = re[3][n], x3i = im[3][n];
        float X0r = x0r + x1r + x2r + x3r, X0i = x0i + x1i + x2i + x3i;
        float X2r = x0r - x1r + x2r - x3r, X2i = x0i - x1i + x2i - x3i;
        float X1r = x0r + x1i - x2r - x3i, X1i = x0i - x1r - x2i + x3r;
        float X3r = x0r - x1i - x2r + x3i, X3i = x0i + x1r - x2i - x3r;
        size_t base = (((size_t)b * 4) * BS + d) * NN + n;
        size_t qs = (size_t)BS * NN;
        Xp[base]          = pack2(X0r * sc, X0i * sc);
        Xp[base + qs]     = pack2(X1r * sc, X1i * sc);
        Xp[base + 2 * qs] = pack2(X2r * sc, X2i * sc);
        Xp[base + 3 * qs] = pack2(X3r * sc, X3i * sc);
    }
}

// ---------------------------------------------------------------------------
// Kernel 2b: one-time B prepack. Emits the exact swizzled LDS tile image the
// GEMM stages with a linear global_load_lds copy.
// Tile (q, nblk, ch): [jl=0..127][col'=0..15] dwords,
//   col' = ((dd>>2) ^ ((jl>>1)&3))*4 + (dd&3),  dd = d within chunk (0..15)
//   j = nblk*128 + jl;  h = j>>1;  j even: (Wr,-Wi), j odd: (Wi,Wr)
// ---------------------------------------------------------------------------
__global__ void pack_b(const float* __restrict__ w, unsigned* __restrict__ Bp) {
    int ch = blockIdx.x, nblk = blockIdx.y, q = blockIdx.z;
    size_t tile = (size_t)((q * 3 + nblk) * 12 + ch);
    const float* wr = w + (size_t)q * BS * BS;
    const float* wi = w + (size_t)(4 + q) * BS * BS;
    for (int r = 0; r < 8; r++) {
        int idx = r * 256 + threadIdx.x;
        int jl = idx & 127, dd = idx >> 7;
        int j = nblk * 128 + jl;
        int h = j >> 1;
        int dg = ch * 16 + dd;
        float Wr = wr[(size_t)dg * BS + h];
        float Wi = wi[(size_t)dg * BS + h];
        unsigned v = (j & 1) ? pack2(Wi, Wr) : pack2(Wr, -Wi);
        int col = ((dd >> 2) ^ ((jl >> 1) & 3)) * 4 + (dd & 3);
        Bp[tile * 2048 + jl * 16 + col] = v;
    }
}

// ---------------------------------------------------------------------------
// Kernel 3: bf16 MFMA GEMM for one complex MLP layer, planes->planes.
// A: packed planes [bq][192][1024]; staged with conflict-free XOR-swizzled LDS
//    (row stride 16 dwords, group ^= (row>>1)&3; writes land 2 lanes/bank).
// B: prepacked swizzled tiles, staged via async global_load_lds (linear).
// Tile 128(M) x 128(J), K chunks of 32 (16 d-pairs), 4 waves x (4x4) 16x16x32.
// ACT 0: ReLU (layer1), 1: softshrink (layer2).
// ---------------------------------------------------------------------------
template <int ACT>
__global__ __launch_bounds__(256) void gemm_mlp(const unsigned* __restrict__ Ap,
                                                const unsigned* __restrict__ Bp,
                                                const float* __restrict__ bias,
                                                unsigned* __restrict__ Cp) {
    __shared__ union {
        struct { unsigned a[128 * 16]; unsigned b[128 * 16]; } st;
        float cbuf[32 * 132];  // epilogue: 32 h-rows x 128 m dwords (+4 pad)
    } sm;

    const int mblk = blockIdx.x;   // 0..7   (m = n-dim, 128 per block)
    const int nblk = blockIdx.y;   // 0..2   (j-dim, 128 per block)
    const int bq   = blockIdx.z;   // 0..255
    const int q    = bq & 3;
    const int tid  = threadIdx.x;
    const int wave = tid >> 6;
    const int lane = tid & 63;
    const int l15  = lane & 15;
    const int quad = lane >> 4;
    const int wm   = (wave & 1) * 64;
    const int wn   = (wave >> 1) * 64;

    // A staging: thread = (d-col sdd, rows n = snb + 16*i). Conflict-free:
    // bank = 16*(l&1) + 4*(g ^ ((l>>1)&3)) + (l>>4) -> 2 lanes/bank.
    const int sdd = tid >> 4;      // 0..15: d within chunk
    const int snb = tid & 15;      // base row
    const int acol = ((sdd >> 2) ^ ((snb >> 1) & 3)) * 4 + (sdd & 3);
    const unsigned* a_gbase = Ap + ((size_t)bq * BS + sdd) * NN + mblk * 128 + snb;

    const unsigned* b_tiles = Bp + (size_t)((q * 3 + nblk) * 12) * 2048;

    // fragment read: group = quad ^ ((row>>1)&3); (row>>1)&3 == (l15>>1)&3
    const int fgrp = (quad ^ ((l15 >> 1) & 3)) * 16;   // byte offset in row

    f32x4 acc[4][4];
    #pragma unroll
    for (int i = 0; i < 4; i++)
        #pragma unroll
        for (int j = 0; j < 4; j++)
            acc[i][j] = (f32x4)0.f;

    for (int ch = 0; ch < 12; ch++) {
        // prefetch A into registers while previous chunk still computes
        unsigned areg[8];
        {
            const unsigned* g = a_gbase + (size_t)(ch * 16) * NN;
            #pragma unroll
            for (int i = 0; i < 8; i++) areg[i] = g[16 * i];
        }
        __syncthreads();
        // --- stage B: linear async copy of prepacked swizzled tile (8 KB) ---
        {
            const unsigned* gb = b_tiles + (size_t)ch * 2048;
            #pragma unroll
            for (int r = 0; r < 2; r++) {
                int c = r * 4 + wave;
                __builtin_amdgcn_global_load_lds(
                    (const __attribute__((address_space(1))) unsigned*)(gb + c * 256 + lane * 4),
                    (__attribute__((address_space(3))) unsigned*)(sm.st.b + c * 256),
                    16, 0, 0);
            }
        }
        // --- stage A: swizzled conflict-free writes ---
        #pragma unroll
        for (int i = 0; i < 8; i++)
            sm.st.a[(snb + 16 * i) * 16 + acol] = areg[i];
        __syncthreads();
        // --- fragments + MFMA ---
        bf16x8 af[4], bfr[4];
        #pragma unroll
        for (int t = 0; t < 4; t++) {
            af[t]  = *(const bf16x8*)((const char*)sm.st.a + (wm + t * 16 + l15) * 64 + fgrp);
            bfr[t] = *(const bf16x8*)((const char*)sm.st.b + (wn + t * 16 + l15) * 64 + fgrp);
        }
        #pragma unroll
        for (int tm = 0; tm < 4; tm++)
            #pragma unroll
            for (int tn = 0; tn < 4; tn++)
                acc[tm][tn] = __builtin_amdgcn_mfma_f32_16x16x32_bf16(af[tm], bfr[tn], acc[tm][tn], 0, 0, 0);
    }

    // --- epilogue: bias + act -> bf16, LDS transpose, coalesced plane stores ---
    for (int p = 0; p < 2; p++) {
        __syncthreads();
        if ((wave >> 1) == p) {
            #pragma unroll
            for (int tn = 0; tn < 4; tn++) {
                int jl = wn + tn * 16 + l15;          // p*64 .. p*64+63
                int jg = nblk * 128 + jl;
                int e = jg & 1, hg = jg >> 1;
                float bv = bias[e * 768 + q * BS + hg];
                int hh = (jl - p * 64) >> 1;          // 0..31
                #pragma unroll
                for (int tm = 0; tm < 4; tm++) {
                    #pragma unroll
                    for (int r = 0; r < 4; r++) {
                        int ml = wm + tm * 16 + quad * 4 + r;
                        float v = acc[tm][tn][r] + bv;
                        if (ACT == 0) v = fmaxf(v, 0.f);
                        else v = (v > LAM) ? (v - LAM) : ((v < -LAM) ? (v + LAM) : 0.f);
                        ((unsigned short*)sm.cbuf)[hh * 264 + ml * 2 + e] = (unsigned short)f2bf(v);
                    }
                }
            }
        }
        __syncthreads();
        {
            int hh = tid >> 3, seg = tid & 7;
            const uint4* src = (const uint4*)((const char*)sm.cbuf + hh * 528 + seg * 64);
            int hgrow = nblk * 64 + p * 32 + hh;
            uint4* dst = (uint4*)(Cp + ((size_t)bq * BS + hgrow) * NN + mblk * 128 + seg * 16);
            uint4 t0 = src[0], t1 = src[1], t2 = src[2], t3 = src[3];
            dst[0] = t0; dst[1] = t1; dst[2] = t2; dst[3] = t3;
        }
    }
}

// ---------------------------------------------------------------------------
// Kernel 4: inverse 4-pt DFT (q) + 1024-pt DIT IFFT + real*1/64 + residual.
// ---------------------------------------------------------------------------
__global__ void inv_fft(const float* __restrict__ x,
                        const unsigned* __restrict__ Yp,
                        float* __restrict__ out) {
    __shared__ float re[4][1024], im[4][1024];
    int d = blockIdx.x, b = blockIdx.y, tid = threadIdx.x;

    for (int q = 0; q < 4; q++) {
        size_t row = (((size_t)b * 4 + q) * BS + d) * NN;
        for (int n = tid; n < NN; n += 256) {
            unsigned v = Yp[row + n];
            re[q][n] = bflo(v);
            im[q][n] = bfhi(v);
        }
    }
    __syncthreads();

    for (int n = tid; n < NN; n += 256) {
        float x0r = re[0][n], x0i = im[0][n];
        float x1r = re[1][n], x1i = im[1][n];
        float x2r = re[2][n], x2i = im[2][n];
        float x3r = re[3][n], x3i = im[3][n];
        float Y0r = x0r + x1r + x2r + x3r, Y0i = x0i + x1i + x2i + x3i;
        float Y2r = x0r - x1r + x2r - x3r, Y2i = x0i - x1i + x2i - x3i;
        float Y1r = x0r - x1i - x2r + x3i, Y1i = x0i + x1r - x2i - x3r;
        float Y3r = x0r + x1i - x2r - x3i, Y3i = x0i - x1r - x2i + x3r;
        re[0][n] = Y0r; im[0][n] = Y0i;
        re[1][n] = Y1r; im[1][n] = Y1i;
        re[2][n] = Y2r; im[2][n] = Y2i;
        re[3][n] = Y3r; im[3][n] = Y3i;
    }
    __syncthreads();

    for (int len = 1; len <= 512; len <<= 1) {
        for (int t = tid; t < 512; t += 256) {
            int j = t & (len - 1);
            int i0 = ((t - j) << 1) + j;
            int i1 = i0 + len;
            float ang = (float)M_PI * (float)j / (float)len;
            float sw, cw;
            __sincosf(ang, &sw, &cw);
            #pragma unroll
            for (int q = 0; q < 4; q++) {
                float br = re[q][i1], bi = im[q][i1];
                float tr = br * cw - bi * sw;
                float ti = br * sw + bi * cw;
                float ar = re[q][i0], ai = im[q][i0];
                re[q][i1] = ar - tr; im[q][i1] = ai - ti;
                re[q][i0] = ar + tr; im[q][i0] = ai + ti;
            }
        }
        __syncthreads();
    }

    const float sc = 1.f / 64.f;
    for (int q = 0; q < 4; q++) {
        size_t row = (((size_t)b * 4 + q) * BS + d) * NN;
        const float* xp = x + row;
        for (int n = tid; n < NN; n += 256) {
            out[row + n] = re[q][n] * sc + xp[n];
        }
    }
}

// ---------------------------------------------------------------------------
extern "C" void kernel_launch(void* const* d_in, const int* in_sizes, int n_in,
                              void* d_out, int out_size, void* d_ws, size_t ws_size,
                              hipStream_t stream) {
    const float* x     = (const float*)d_in[0];
    const float* w1    = (const float*)d_in[1];
    const float* w2    = (const float*)d_in[2];
    const float* b1    = (const float*)d_in[3];
    const float* b2    = (const float*)d_in[4];
    const float* gamma = (const float*)d_in[5];
    const float* beta  = (const float*)d_in[6];

    unsigned* Xp = (unsigned*)d_ws;                       // packed bf16 complex planes
    float* mu    = (float*)d_ws + (size_t)BB * CC * NN;   // after 50.3M dwords
    float* rstd  = mu + (size_t)BB * NN;
    unsigned* Bp1 = (unsigned*)(rstd + (size_t)BB * NN);  // 294912 dwords each
    unsigned* Bp2 = Bp1 + (size_t)4 * 3 * 12 * 2048;
    unsigned* Hp = (unsigned*)d_out;                      // H planes alias d_out
    unsigned* Yp = Xp;                                    // Y reuses X region

    pack_b<<<dim3(12, 3, 4), 256, 0, stream>>>(w1, Bp1);
    pack_b<<<dim3(12, 3, 4), 256, 0, stream>>>(w2, Bp2);
    ln_stats<<<dim3(NN / 64, BB), 256, 0, stream>>>(x, mu, rstd);
    fwd_fft<<<dim3(BS, BB), 256, 0, stream>>>(x, mu, rstd, gamma, beta, Xp);
    gemm_mlp<0><<<dim3(8, 3, 256), 256, 0, stream>>>(Xp, Bp1, b1, Hp);
    gemm_mlp<1><<<dim3(8, 3, 256), 256, 0, stream>>>(Hp, Bp2, b2, Yp);
    inv_fft<<<dim3(BS, BB), 256, 0, stream>>>(x, Yp, (float*)d_out);
}

// Round 2
// 991.833 us; speedup vs baseline: 1.7040x; 1.3878x over previous
//
#include <hip/hip_runtime.h>
#include <math.h>

#define BB 64
#define CC 768
#define NN 1024
#define BS 192
#define EPS 1e-5f
#define LAM 0.01f

typedef float  f32x4  __attribute__((ext_vector_type(4)));
typedef short  bf16x8 __attribute__((ext_vector_type(8)));

__device__ inline unsigned f2bf(float x) {
    unsigned u = __float_as_uint(x);
    u += 0x7fff + ((u >> 16) & 1);   // RNE
    return u >> 16;
}
__device__ inline unsigned pack2(float r, float i) { return f2bf(r) | (f2bf(i) << 16); }
__device__ inline float bflo(unsigned v) { return __uint_as_float(v << 16); }
__device__ inline float bfhi(unsigned v) { return __uint_as_float(v & 0xffff0000u); }

// LDS bank swizzle on float2 index: XOR bits 4-5 into bits 2-3.
// Gives <=4 lanes per bank-pair for every stage stride (256/64/16/4) and for
// the contiguous 4-element register-tail accesses (bits 0-1 untouched, so
// blocks of 4 float2 stay contiguous -> b128-able).
__device__ inline int swz(int i) { return i ^ (((i >> 4) & 3) << 2); }

// ---------------------------------------------------------------------------
// Kernel 1: LayerNorm statistics per (b, n).
// ---------------------------------------------------------------------------
__global__ void ln_stats(const float* __restrict__ x,
                         float* __restrict__ mu, float* __restrict__ rstd) {
    int tn = threadIdx.x & 63, tc = threadIdx.x >> 6;
    int n = blockIdx.x * 64 + tn, b = blockIdx.y;
    const float* xp = x + (size_t)b * CC * NN + n;
    float s = 0.f, ss = 0.f;
    for (int c = tc; c < CC; c += 4) {
        float v = xp[(size_t)c * NN];
        s += v; ss += v * v;
    }
    __shared__ float sm[4][64], sq[4][64];
    sm[tc][tn] = s; sq[tc][tn] = ss;
    __syncthreads();
    if (tc == 0) {
        s  = sm[0][tn] + sm[1][tn] + sm[2][tn] + sm[3][tn];
        ss = sq[0][tn] + sq[1][tn] + sq[2][tn] + sq[3][tn];
        float m = s * (1.f / 768.f);
        float v = ss * (1.f / 768.f) - m * m;
        mu[b * NN + n] = m;
        rstd[b * NN + n] = rsqrtf(v + EPS);
    }
}

// ---------------------------------------------------------------------------
// Kernel 2: LN-apply + 1024-pt radix-4 DIF FFT (n) + 4-pt DFT (q) + 1/64.
// Stages L=256,64,16,4 in LDS (float2, swizzled); the twiddle-free L=1 stage
// is fused with the q-DFT + bf16 pack in registers (uint4 stores).
// Output: packed bf16 complex planes Xp[(b*4+q)*192 + d][n], dword=(re|im<<16).
// n is base-4 digit-reversed (MLP is n-order agnostic; inverse undoes it).
// ---------------------------------------------------------------------------
__global__ void fwd_fft(const float* __restrict__ x,
                        const float* __restrict__ mu_, const float* __restrict__ rs_,
                        const float* __restrict__ gamma, const float* __restrict__ beta,
                        unsigned* __restrict__ Xp) {
    __shared__ float2 bufs[4][1024];
    int d = blockIdx.x, b = blockIdx.y, tid = threadIdx.x;

    const float* mp = mu_ + b * NN;
    const float* rp = rs_ + b * NN;
    #pragma unroll
    for (int q = 0; q < 4; q++) {
        int c = q * BS + d;
        float g = gamma[c], be = beta[c];
        const float* xp = x + ((size_t)b * CC + c) * NN;
        #pragma unroll
        for (int k = 0; k < 4; k++) {
            int n = tid + 256 * k;
            float v = (xp[n] - mp[n]) * rp[n] * g + be;
            bufs[q][swz(n)] = make_float2(v, 0.f);
        }
    }
    __syncthreads();

    // radix-4 DIF stages, L = 256, 64, 16, 4
    #pragma unroll
    for (int sL = 0; sL < 4; sL++) {
        const int L = 256 >> (2 * sL);
        int j = tid & (L - 1);
        int base = ((tid - j) << 2) + j;
        float s1, c1;
        __sincosf(-(float)M_PI * 0.5f * (float)j / (float)L, &s1, &c1);
        float c2 = c1 * c1 - s1 * s1, s2 = 2.f * c1 * s1;
        float c3 = c2 * c1 - s2 * s1, s3 = c2 * s1 + s2 * c1;
        #pragma unroll
        for (int q = 0; q < 4; q++) {
            float2 a  = bufs[q][swz(base)];
            float2 bb = bufs[q][swz(base + L)];
            float2 cc = bufs[q][swz(base + 2 * L)];
            float2 dd = bufs[q][swz(base + 3 * L)];
            float t0r = a.x + cc.x, t0i = a.y + cc.y;
            float t1r = a.x - cc.x, t1i = a.y - cc.y;
            float t2r = bb.x + dd.x, t2i = bb.y + dd.y;
            float t3r = bb.x - dd.x, t3i = bb.y - dd.y;
            float X0r = t0r + t2r, X0i = t0i + t2i;
            float X2r = t0r - t2r, X2i = t0i - t2i;
            float X1r = t1r + t3i, X1i = t1i - t3r;   // t1 - i*t3
            float X3r = t1r - t3i, X3i = t1i + t3r;   // t1 + i*t3
            bufs[q][swz(base)]         = make_float2(X0r, X0i);
            bufs[q][swz(base + L)]     = make_float2(X1r * c1 - X1i * s1, X1r * s1 + X1i * c1);
            bufs[q][swz(base + 2 * L)] = make_float2(X2r * c2 - X2i * s2, X2r * s2 + X2i * c2);
            bufs[q][swz(base + 3 * L)] = make_float2(X3r * c3 - X3i * s3, X3r * s3 + X3i * c3);
        }
        __syncthreads();
    }

    // tail: L=1 butterfly (no twiddles) + q-DFT + scale + pack + uint4 stores
    float Xr[4][4], Xi[4][4];
    int i0 = swz(4 * tid);
    #pragma unroll
    for (int q = 0; q < 4; q++) {
        const float4* p = (const float4*)&bufs[q][i0];
        float4 u0 = p[0], u1 = p[1];
        float t0r = u0.x + u1.x, t0i = u0.y + u1.y;
        float t1r = u0.x - u1.x, t1i = u0.y - u1.y;
        float t2r = u0.z + u1.z, t2i = u0.w + u1.w;
        float t3r = u0.z - u1.z, t3i = u0.w - u1.w;
        Xr[q][0] = t0r + t2r; Xi[q][0] = t0i + t2i;
        Xr[q][1] = t1r + t3i; Xi[q][1] = t1i - t3r;   // t1 - i*t3
        Xr[q][2] = t0r - t2r; Xi[q][2] = t0i - t2i;
        Xr[q][3] = t1r - t3i; Xi[q][3] = t1i + t3r;   // t1 + i*t3
    }
    const float sc = 1.f / 64.f;
    unsigned o0[4], o1[4], o2[4], o3[4];
    #pragma unroll
    for (int m = 0; m < 4; m++) {
        float x0r = Xr[0][m], x0i = Xi[0][m];
        float x1r = Xr[1][m], x1i = Xi[1][m];
        float x2r = Xr[2][m], x2i = Xi[2][m];
        float x3r = Xr[3][m], x3i = Xi[3][m];
        float X0r = x0r + x1r + x2r + x3r, X0i = x0i + x1i + x2i + x3i;
        float X2r = x0r - x1r + x2r - x3r, X2i = x0i - x1i + x2i - x3i;
        float X1r = x0r + x1i - x2r - x3i, X1i = x0i - x1r - x2i + x3r;
        float X3r = x0r - x1i - x2r + x3i, X3i = x0i + x1r - x2i - x3r;
        o0[m] = pack2(X0r * sc, X0i * sc);
        o1[m] = pack2(X1r * sc, X1i * sc);
        o2[m] = pack2(X2r * sc, X2i * sc);
        o3[m] = pack2(X3r * sc, X3i * sc);
    }
    size_t qs = (size_t)BS * NN;
    size_t base = (((size_t)b * 4) * BS + d) * NN + 4 * tid;
    *(uint4*)(Xp + base)          = make_uint4(o0[0], o0[1], o0[2], o0[3]);
    *(uint4*)(Xp + base + qs)     = make_uint4(o1[0], o1[1], o1[2], o1[3]);
    *(uint4*)(Xp + base + 2 * qs) = make_uint4(o2[0], o2[1], o2[2], o2[3]);
    *(uint4*)(Xp + base + 3 * qs) = make_uint4(o3[0], o3[1], o3[2], o3[3]);
}

// ---------------------------------------------------------------------------
// Kernel 2b: one-time B prepack (unchanged).
// ---------------------------------------------------------------------------
__global__ void pack_b(const float* __restrict__ w, unsigned* __restrict__ Bp) {
    int ch = blockIdx.x, nblk = blockIdx.y, q = blockIdx.z;
    size_t tile = (size_t)((q * 3 + nblk) * 12 + ch);
    const float* wr = w + (size_t)q * BS * BS;
    const float* wi = w + (size_t)(4 + q) * BS * BS;
    for (int r = 0; r < 8; r++) {
        int idx = r * 256 + threadIdx.x;
        int jl = idx & 127, dd = idx >> 7;
        int j = nblk * 128 + jl;
        int h = j >> 1;
        int dg = ch * 16 + dd;
        float Wr = wr[(size_t)dg * BS + h];
        float Wi = wi[(size_t)dg * BS + h];
        unsigned v = (j & 1) ? pack2(Wi, Wr) : pack2(Wr, -Wi);
        int col = ((dd >> 2) ^ ((jl >> 1) & 3)) * 4 + (dd & 3);
        Bp[tile * 2048 + jl * 16 + col] = v;
    }
}

// ---------------------------------------------------------------------------
// Kernel 3: bf16 MFMA GEMM (unchanged from R1).
// ---------------------------------------------------------------------------
template <int ACT>
__global__ __launch_bounds__(256) void gemm_mlp(const unsigned* __restrict__ Ap,
                                                const unsigned* __restrict__ Bp,
                                                const float* __restrict__ bias,
                                                unsigned* __restrict__ Cp) {
    __shared__ union {
        struct { unsigned a[128 * 16]; unsigned b[128 * 16]; } st;
        float cbuf[32 * 132];
    } sm;

    const int mblk = blockIdx.x;
    const int nblk = blockIdx.y;
    const int bq   = blockIdx.z;
    const int q    = bq & 3;
    const int tid  = threadIdx.x;
    const int wave = tid >> 6;
    const int lane = tid & 63;
    const int l15  = lane & 15;
    const int quad = lane >> 4;
    const int wm   = (wave & 1) * 64;
    const int wn   = (wave >> 1) * 64;

    const int sdd = tid >> 4;
    const int snb = tid & 15;
    const int acol = ((sdd >> 2) ^ ((snb >> 1) & 3)) * 4 + (sdd & 3);
    const unsigned* a_gbase = Ap + ((size_t)bq * BS + sdd) * NN + mblk * 128 + snb;

    const unsigned* b_tiles = Bp + (size_t)((q * 3 + nblk) * 12) * 2048;

    const int fgrp = (quad ^ ((l15 >> 1) & 3)) * 16;

    f32x4 acc[4][4];
    #pragma unroll
    for (int i = 0; i < 4; i++)
        #pragma unroll
        for (int j = 0; j < 4; j++)
            acc[i][j] = (f32x4)0.f;

    for (int ch = 0; ch < 12; ch++) {
        unsigned areg[8];
        {
            const unsigned* g = a_gbase + (size_t)(ch * 16) * NN;
            #pragma unroll
            for (int i = 0; i < 8; i++) areg[i] = g[16 * i];
        }
        __syncthreads();
        {
            const unsigned* gb = b_tiles + (size_t)ch * 2048;
            #pragma unroll
            for (int r = 0; r < 2; r++) {
                int c = r * 4 + wave;
                __builtin_amdgcn_global_load_lds(
                    (const __attribute__((address_space(1))) unsigned*)(gb + c * 256 + lane * 4),
                    (__attribute__((address_space(3))) unsigned*)(sm.st.b + c * 256),
                    16, 0, 0);
            }
        }
        #pragma unroll
        for (int i = 0; i < 8; i++)
            sm.st.a[(snb + 16 * i) * 16 + acol] = areg[i];
        __syncthreads();
        bf16x8 af[4], bfr[4];
        #pragma unroll
        for (int t = 0; t < 4; t++) {
            af[t]  = *(const bf16x8*)((const char*)sm.st.a + (wm + t * 16 + l15) * 64 + fgrp);
            bfr[t] = *(const bf16x8*)((const char*)sm.st.b + (wn + t * 16 + l15) * 64 + fgrp);
        }
        #pragma unroll
        for (int tm = 0; tm < 4; tm++)
            #pragma unroll
            for (int tn = 0; tn < 4; tn++)
                acc[tm][tn] = __builtin_amdgcn_mfma_f32_16x16x32_bf16(af[tm], bfr[tn], acc[tm][tn], 0, 0, 0);
    }

    for (int p = 0; p < 2; p++) {
        __syncthreads();
        if ((wave >> 1) == p) {
            #pragma unroll
            for (int tn = 0; tn < 4; tn++) {
                int jl = wn + tn * 16 + l15;
                int jg = nblk * 128 + jl;
                int e = jg & 1, hg = jg >> 1;
                float bv = bias[e * 768 + q * BS + hg];
                int hh = (jl - p * 64) >> 1;
                #pragma unroll
                for (int tm = 0; tm < 4; tm++) {
                    #pragma unroll
                    for (int r = 0; r < 4; r++) {
                        int ml = wm + tm * 16 + quad * 4 + r;
                        float v = acc[tm][tn][r] + bv;
                        if (ACT == 0) v = fmaxf(v, 0.f);
                        else v = (v > LAM) ? (v - LAM) : ((v < -LAM) ? (v + LAM) : 0.f);
                        ((unsigned short*)sm.cbuf)[hh * 264 + ml * 2 + e] = (unsigned short)f2bf(v);
                    }
                }
            }
        }
        __syncthreads();
        {
            int hh = tid >> 3, seg = tid & 7;
            const uint4* src = (const uint4*)((const char*)sm.cbuf + hh * 528 + seg * 64);
            int hgrow = nblk * 64 + p * 32 + hh;
            uint4* dst = (uint4*)(Cp + ((size_t)bq * BS + hgrow) * NN + mblk * 128 + seg * 16);
            uint4 t0 = src[0], t1 = src[1], t2 = src[2], t3 = src[3];
            dst[0] = t0; dst[1] = t1; dst[2] = t2; dst[3] = t3;
        }
    }
}

// ---------------------------------------------------------------------------
// Kernel 4: inverse. uint4 loads + q-IDFT + L=1 inverse butterfly in regs,
// then radix-4 DIT stages L=4,16,64,256 in LDS, then 1/64 + residual store.
// ---------------------------------------------------------------------------
__global__ void inv_fft(const float* __restrict__ x,
                        const unsigned* __restrict__ Yp,
                        float* __restrict__ out) {
    __shared__ float2 bufs[4][1024];
    int d = blockIdx.x, b = blockIdx.y, tid = threadIdx.x;

    // head: load 4 n per q, q-inverse-DFT, L=1 inverse butterfly, write LDS
    float Ar[4][4], Ai[4][4];
    size_t qs = (size_t)BS * NN;
    size_t rowb = (((size_t)b * 4) * BS + d) * NN + 4 * tid;
    #pragma unroll
    for (int q = 0; q < 4; q++) {
        uint4 v = *(const uint4*)(Yp + rowb + (size_t)q * qs);
        Ar[q][0] = bflo(v.x); Ai[q][0] = bfhi(v.x);
        Ar[q][1] = bflo(v.y); Ai[q][1] = bfhi(v.y);
        Ar[q][2] = bflo(v.z); Ai[q][2] = bfhi(v.z);
        Ar[q][3] = bflo(v.w); Ai[q][3] = bfhi(v.w);
    }
    #pragma unroll
    for (int m = 0; m < 4; m++) {
        float x0r = Ar[0][m], x0i = Ai[0][m];
        float x1r = Ar[1][m], x1i = Ai[1][m];
        float x2r = Ar[2][m], x2i = Ai[2][m];
        float x3r = Ar[3][m], x3i = Ai[3][m];
        float Y0r = x0r + x1r + x2r + x3r, Y0i = x0i + x1i + x2i + x3i;
        float Y2r = x0r - x1r + x2r - x3r, Y2i = x0i - x1i + x2i - x3i;
        float Y1r = x0r - x1i - x2r + x3i, Y1i = x0i + x1r - x2i - x3r;
        float Y3r = x0r + x1i - x2r - x3i, Y3i = x0i - x1r - x2i + x3r;
        Ar[0][m] = Y0r; Ai[0][m] = Y0i;
        Ar[1][m] = Y1r; Ai[1][m] = Y1i;
        Ar[2][m] = Y2r; Ai[2][m] = Y2i;
        Ar[3][m] = Y3r; Ai[3][m] = Y3i;
    }
    int i0 = swz(4 * tid);
    #pragma unroll
    for (int q = 0; q < 4; q++) {
        float t0r = Ar[q][0] + Ar[q][2], t0i = Ai[q][0] + Ai[q][2];
        float t1r = Ar[q][0] - Ar[q][2], t1i = Ai[q][0] - Ai[q][2];
        float t2r = Ar[q][1] + Ar[q][3], t2i = Ai[q][1] + Ai[q][3];
        float t3r = Ar[q][1] - Ar[q][3], t3i = Ai[q][1] - Ai[q][3];
        float4* p = (float4*)&bufs[q][i0];
        // x0 = t0+t2; x1 = t1 + i*t3; x2 = t0-t2; x3 = t1 - i*t3
        p[0] = make_float4(t0r + t2r, t0i + t2i, t1r - t3i, t1i + t3r);
        p[1] = make_float4(t0r - t2r, t0i - t2i, t1r + t3i, t1i - t3r);
    }
    __syncthreads();

    // radix-4 DIT stages, L = 4, 16, 64, 256 (conjugate twiddles, pre-multiply)
    #pragma unroll
    for (int sL = 0; sL < 4; sL++) {
        const int L = 4 << (2 * sL);
        int j = tid & (L - 1);
        int base = ((tid - j) << 2) + j;
        float s1, c1;
        __sincosf((float)M_PI * 0.5f * (float)j / (float)L, &s1, &c1);
        float c2 = c1 * c1 - s1 * s1, s2 = 2.f * c1 * s1;
        float c3 = c2 * c1 - s2 * s1, s3 = c2 * s1 + s2 * c1;
        #pragma unroll
        for (int q = 0; q < 4; q++) {
            float2 y0 = bufs[q][swz(base)];
            float2 y1 = bufs[q][swz(base + L)];
            float2 y2 = bufs[q][swz(base + 2 * L)];
            float2 y3 = bufs[q][swz(base + 3 * L)];
            float A1r = y1.x * c1 - y1.y * s1, A1i = y1.x * s1 + y1.y * c1;
            float A2r = y2.x * c2 - y2.y * s2, A2i = y2.x * s2 + y2.y * c2;
            float A3r = y3.x * c3 - y3.y * s3, A3i = y3.x * s3 + y3.y * c3;
            float t0r = y0.x + A2r, t0i = y0.y + A2i;
            float t1r = y0.x - A2r, t1i = y0.y - A2i;
            float t2r = A1r + A3r, t2i = A1i + A3i;
            float t3r = A1r - A3r, t3i = A1i - A3i;
            bufs[q][swz(base)]         = make_float2(t0r + t2r, t0i + t2i);
            bufs[q][swz(base + L)]     = make_float2(t1r - t3i, t1i + t3r);  // t1 + i*t3
            bufs[q][swz(base + 2 * L)] = make_float2(t0r - t2r, t0i - t2i);
            bufs[q][swz(base + 3 * L)] = make_float2(t1r + t3i, t1i - t3r);  // t1 - i*t3
        }
        __syncthreads();
    }

    // tail: scale + residual + store
    const float sc = 1.f / 64.f;
    #pragma unroll
    for (int q = 0; q < 4; q++) {
        size_t row = (((size_t)b * 4 + q) * BS + d) * NN;
        const float* xp = x + row;
        #pragma unroll
        for (int k = 0; k < 4; k++) {
            int n = tid + 256 * k;
            out[row + n] = bufs[q][swz(n)].x * sc + xp[n];
        }
    }
}

// ---------------------------------------------------------------------------
extern "C" void kernel_launch(void* const* d_in, const int* in_sizes, int n_in,
                              void* d_out, int out_size, void* d_ws, size_t ws_size,
                              hipStream_t stream) {
    const float* x     = (const float*)d_in[0];
    const float* w1    = (const float*)d_in[1];
    const float* w2    = (const float*)d_in[2];
    const float* b1    = (const float*)d_in[3];
    const float* b2    = (const float*)d_in[4];
    const float* gamma = (const float*)d_in[5];
    const float* beta  = (const float*)d_in[6];

    unsigned* Xp = (unsigned*)d_ws;
    float* mu    = (float*)d_ws + (size_t)BB * CC * NN;
    float* rstd  = mu + (size_t)BB * NN;
    unsigned* Bp1 = (unsigned*)(rstd + (size_t)BB * NN);
    unsigned* Bp2 = Bp1 + (size_t)4 * 3 * 12 * 2048;
    unsigned* Hp = (unsigned*)d_out;
    unsigned* Yp = Xp;

    pack_b<<<dim3(12, 3, 4), 256, 0, stream>>>(w1, Bp1);
    pack_b<<<dim3(12, 3, 4), 256, 0, stream>>>(w2, Bp2);
    ln_stats<<<dim3(NN / 64, BB), 256, 0, stream>>>(x, mu, rstd);
    fwd_fft<<<dim3(BS, BB), 256, 0, stream>>>(x, mu, rstd, gamma, beta, Xp);
    gemm_mlp<0><<<dim3(8, 3, 256), 256, 0, stream>>>(Xp, Bp1, b1, Hp);
    gemm_mlp<1><<<dim3(8, 3, 256), 256, 0, stream>>>(Hp, Bp2, b2, Yp);
    inv_fft<<<dim3(BS, BB), 256, 0, stream>>>(x, Yp, (float*)d_out);
}

// Round 3
// 865.263 us; speedup vs baseline: 1.9533x; 1.1463x over previous
//
#include <hip/hip_runtime.h>
#include <math.h>

#define BB 64
#define CC 768
#define NN 1024
#define BS 192
#define EPS 1e-5f
#define LAM 0.01f

typedef float  f32x4  __attribute__((ext_vector_type(4)));
typedef short  bf16x8 __attribute__((ext_vector_type(8)));

__device__ inline unsigned f2bf(float x) {
    unsigned u = __float_as_uint(x);
    u += 0x7fff + ((u >> 16) & 1);   // RNE
    return u >> 16;
}
__device__ inline unsigned pack2(float r, float i) { return f2bf(r) | (f2bf(i) << 16); }
__device__ inline float bflo(unsigned v) { return __uint_as_float(v << 16); }
__device__ inline float bfhi(unsigned v) { return __uint_as_float(v & 0xffff0000u); }

// LDS bank swizzle on float2 index: XOR bits 4-5 into bits 2-3.
__device__ inline int swz(int i) { return i ^ (((i >> 4) & 3) << 2); }

// ---------------------------------------------------------------------------
// Kernel 1: LayerNorm statistics per (b, n).
// ---------------------------------------------------------------------------
__global__ void ln_stats(const float* __restrict__ x,
                         float* __restrict__ mu, float* __restrict__ rstd) {
    int tn = threadIdx.x & 63, tc = threadIdx.x >> 6;
    int n = blockIdx.x * 64 + tn, b = blockIdx.y;
    const float* xp = x + (size_t)b * CC * NN + n;
    float s = 0.f, ss = 0.f;
    for (int c = tc; c < CC; c += 4) {
        float v = xp[(size_t)c * NN];
        s += v; ss += v * v;
    }
    __shared__ float sm[4][64], sq[4][64];
    sm[tc][tn] = s; sq[tc][tn] = ss;
    __syncthreads();
    if (tc == 0) {
        s  = sm[0][tn] + sm[1][tn] + sm[2][tn] + sm[3][tn];
        ss = sq[0][tn] + sq[1][tn] + sq[2][tn] + sq[3][tn];
        float m = s * (1.f / 768.f);
        float v = ss * (1.f / 768.f) - m * m;
        mu[b * NN + n] = m;
        rstd[b * NN + n] = rsqrtf(v + EPS);
    }
}

// ---------------------------------------------------------------------------
// Kernel 2: LN-apply + 1024-pt radix-4 DIF FFT (n) + 4-pt DFT (q) + 1/64.
// ---------------------------------------------------------------------------
__global__ void fwd_fft(const float* __restrict__ x,
                        const float* __restrict__ mu_, const float* __restrict__ rs_,
                        const float* __restrict__ gamma, const float* __restrict__ beta,
                        unsigned* __restrict__ Xp) {
    __shared__ float2 bufs[4][1024];
    int d = blockIdx.x, b = blockIdx.y, tid = threadIdx.x;

    const float* mp = mu_ + b * NN;
    const float* rp = rs_ + b * NN;
    #pragma unroll
    for (int q = 0; q < 4; q++) {
        int c = q * BS + d;
        float g = gamma[c], be = beta[c];
        const float* xp = x + ((size_t)b * CC + c) * NN;
        #pragma unroll
        for (int k = 0; k < 4; k++) {
            int n = tid + 256 * k;
            float v = (xp[n] - mp[n]) * rp[n] * g + be;
            bufs[q][swz(n)] = make_float2(v, 0.f);
        }
    }
    __syncthreads();

    #pragma unroll
    for (int sL = 0; sL < 4; sL++) {
        const int L = 256 >> (2 * sL);
        int j = tid & (L - 1);
        int base = ((tid - j) << 2) + j;
        float s1, c1;
        __sincosf(-(float)M_PI * 0.5f * (float)j / (float)L, &s1, &c1);
        float c2 = c1 * c1 - s1 * s1, s2 = 2.f * c1 * s1;
        float c3 = c2 * c1 - s2 * s1, s3 = c2 * s1 + s2 * c1;
        #pragma unroll
        for (int q = 0; q < 4; q++) {
            float2 a  = bufs[q][swz(base)];
            float2 bb = bufs[q][swz(base + L)];
            float2 cc = bufs[q][swz(base + 2 * L)];
            float2 dd = bufs[q][swz(base + 3 * L)];
            float t0r = a.x + cc.x, t0i = a.y + cc.y;
            float t1r = a.x - cc.x, t1i = a.y - cc.y;
            float t2r = bb.x + dd.x, t2i = bb.y + dd.y;
            float t3r = bb.x - dd.x, t3i = bb.y - dd.y;
            float X0r = t0r + t2r, X0i = t0i + t2i;
            float X2r = t0r - t2r, X2i = t0i - t2i;
            float X1r = t1r + t3i, X1i = t1i - t3r;
            float X3r = t1r - t3i, X3i = t1i + t3r;
            bufs[q][swz(base)]         = make_float2(X0r, X0i);
            bufs[q][swz(base + L)]     = make_float2(X1r * c1 - X1i * s1, X1r * s1 + X1i * c1);
            bufs[q][swz(base + 2 * L)] = make_float2(X2r * c2 - X2i * s2, X2r * s2 + X2i * c2);
            bufs[q][swz(base + 3 * L)] = make_float2(X3r * c3 - X3i * s3, X3r * s3 + X3i * c3);
        }
        __syncthreads();
    }

    float Xr[4][4], Xi[4][4];
    int i0 = swz(4 * tid);
    #pragma unroll
    for (int q = 0; q < 4; q++) {
        const float4* p = (const float4*)&bufs[q][i0];
        float4 u0 = p[0], u1 = p[1];
        float t0r = u0.x + u1.x, t0i = u0.y + u1.y;
        float t1r = u0.x - u1.x, t1i = u0.y - u1.y;
        float t2r = u0.z + u1.z, t2i = u0.w + u1.w;
        float t3r = u0.z - u1.z, t3i = u0.w - u1.w;
        Xr[q][0] = t0r + t2r; Xi[q][0] = t0i + t2i;
        Xr[q][1] = t1r + t3i; Xi[q][1] = t1i - t3r;
        Xr[q][2] = t0r - t2r; Xi[q][2] = t0i - t2i;
        Xr[q][3] = t1r - t3i; Xi[q][3] = t1i + t3r;
    }
    const float sc = 1.f / 64.f;
    unsigned o0[4], o1[4], o2[4], o3[4];
    #pragma unroll
    for (int m = 0; m < 4; m++) {
        float x0r = Xr[0][m], x0i = Xi[0][m];
        float x1r = Xr[1][m], x1i = Xi[1][m];
        float x2r = Xr[2][m], x2i = Xi[2][m];
        float x3r = Xr[3][m], x3i = Xi[3][m];
        float X0r = x0r + x1r + x2r + x3r, X0i = x0i + x1i + x2i + x3i;
        float X2r = x0r - x1r + x2r - x3r, X2i = x0i - x1i + x2i - x3i;
        float X1r = x0r + x1i - x2r - x3i, X1i = x0i - x1r - x2i + x3r;
        float X3r = x0r - x1i - x2r + x3i, X3i = x0i + x1r - x2i - x3r;
        o0[m] = pack2(X0r * sc, X0i * sc);
        o1[m] = pack2(X1r * sc, X1i * sc);
        o2[m] = pack2(X2r * sc, X2i * sc);
        o3[m] = pack2(X3r * sc, X3i * sc);
    }
    size_t qs = (size_t)BS * NN;
    size_t base = (((size_t)b * 4) * BS + d) * NN + 4 * tid;
    *(uint4*)(Xp + base)          = make_uint4(o0[0], o0[1], o0[2], o0[3]);
    *(uint4*)(Xp + base + qs)     = make_uint4(o1[0], o1[1], o1[2], o1[3]);
    *(uint4*)(Xp + base + 2 * qs) = make_uint4(o2[0], o2[1], o2[2], o2[3]);
    *(uint4*)(Xp + base + 3 * qs) = make_uint4(o3[0], o3[1], o3[2], o3[3]);
}

// ---------------------------------------------------------------------------
// Kernel 2b: one-time B prepack (unchanged).
// ---------------------------------------------------------------------------
__global__ void pack_b(const float* __restrict__ w, unsigned* __restrict__ Bp) {
    int ch = blockIdx.x, nblk = blockIdx.y, q = blockIdx.z;
    size_t tile = (size_t)((q * 3 + nblk) * 12 + ch);
    const float* wr = w + (size_t)q * BS * BS;
    const float* wi = w + (size_t)(4 + q) * BS * BS;
    for (int r = 0; r < 8; r++) {
        int idx = r * 256 + threadIdx.x;
        int jl = idx & 127, dd = idx >> 7;
        int j = nblk * 128 + jl;
        int h = j >> 1;
        int dg = ch * 16 + dd;
        float Wr = wr[(size_t)dg * BS + h];
        float Wi = wi[(size_t)dg * BS + h];
        unsigned v = (j & 1) ? pack2(Wi, Wr) : pack2(Wr, -Wi);
        int col = ((dd >> 2) ^ ((jl >> 1) & 3)) * 4 + (dd & 3);
        Bp[tile * 2048 + jl * 16 + col] = v;
    }
}

// ---------------------------------------------------------------------------
// Kernel 3: bf16 MFMA GEMM. Operand-swapped MFMA: mfma(B_frag, A_frag) puts
// the j-dim on (quad,reg) and the m-dim on l15, so each lane holds
// (h,re),(h,im),(h+1,re),(h+1,im) for consecutive regs -> output dwords are
// packed in registers and stored directly. No epilogue LDS, no transpose.
// ---------------------------------------------------------------------------
template <int ACT>
__global__ __launch_bounds__(256) void gemm_mlp(const unsigned* __restrict__ Ap,
                                                const unsigned* __restrict__ Bp,
                                                const float* __restrict__ bias,
                                                unsigned* __restrict__ Cp) {
    __shared__ unsigned sa[2048];   // A tile [m=128][kcol=16 dwords, swizzled]
    __shared__ unsigned sb[2048];   // B tile [j=128][kcol=16 dwords, swizzled]

    const int mblk = blockIdx.x;
    const int nblk = blockIdx.y;
    const int bq   = blockIdx.z;
    const int q    = bq & 3;
    const int tid  = threadIdx.x;
    const int wave = tid >> 6;
    const int lane = tid & 63;
    const int l15  = lane & 15;
    const int quad = lane >> 4;
    const int wm   = (wave & 1) * 64;
    const int wn   = (wave >> 1) * 64;

    // A staging: thread = (d-col sdd, m rows snb + 16*i), swizzled (2 lanes/bank)
    const int sdd = tid >> 4;
    const int snb = tid & 15;
    const int acol = ((sdd >> 2) ^ ((snb >> 1) & 3)) * 4 + (sdd & 3);
    const unsigned* a_gbase = Ap + ((size_t)bq * BS + sdd) * NN + mblk * 128 + snb;

    const unsigned* b_tiles = Bp + (size_t)((q * 3 + nblk) * 12) * 2048;

    const int fgrp = (quad ^ ((l15 >> 1) & 3)) * 16;

    f32x4 acc[4][4];   // acc[tn][tm]
    #pragma unroll
    for (int i = 0; i < 4; i++)
        #pragma unroll
        for (int j = 0; j < 4; j++)
            acc[i][j] = (f32x4)0.f;

    unsigned areg[8];
    {
        const unsigned* g = a_gbase;
        #pragma unroll
        for (int i = 0; i < 8; i++) areg[i] = g[16 * i];
    }

    for (int ch = 0; ch < 12; ch++) {
        __syncthreads();
        // stage B: linear async copy of prepacked swizzled tile (8 KB)
        {
            const unsigned* gb = b_tiles + (size_t)ch * 2048;
            #pragma unroll
            for (int r = 0; r < 2; r++) {
                int c = r * 4 + wave;
                __builtin_amdgcn_global_load_lds(
                    (const __attribute__((address_space(1))) unsigned*)(gb + c * 256 + lane * 4),
                    (__attribute__((address_space(3))) unsigned*)(sb + c * 256),
                    16, 0, 0);
            }
        }
        // stage A from prefetched registers (swizzled, conflict-free)
        #pragma unroll
        for (int i = 0; i < 8; i++)
            sa[(snb + 16 * i) * 16 + acol] = areg[i];
        __syncthreads();
        // fragments
        bf16x8 af[4], bfr[4];
        #pragma unroll
        for (int t = 0; t < 4; t++) {
            af[t]  = *(const bf16x8*)((const char*)sa + (wm + t * 16 + l15) * 64 + fgrp);
            bfr[t] = *(const bf16x8*)((const char*)sb + (wn + t * 16 + l15) * 64 + fgrp);
        }
        // prefetch next A chunk early -> latency hides under MFMA + barrier
        if (ch < 11) {
            const unsigned* g = a_gbase + (size_t)((ch + 1) * 16) * NN;
            #pragma unroll
            for (int i = 0; i < 8; i++) areg[i] = g[16 * i];
        }
        // operand-swapped MFMA: j on rows(quad,reg), m on cols(l15)
        #pragma unroll
        for (int tn = 0; tn < 4; tn++)
            #pragma unroll
            for (int tm = 0; tm < 4; tm++)
                acc[tn][tm] = __builtin_amdgcn_mfma_f32_16x16x32_bf16(bfr[tn], af[tm], acc[tn][tm], 0, 0, 0);
    }

    // epilogue: bias + act + pack in registers, direct coalesced dword stores
    #pragma unroll
    for (int tn = 0; tn < 4; tn++) {
        int jb = wn + tn * 16 + quad * 4;       // j within block, r spans jb..jb+3
        int hg = nblk * 64 + (jb >> 1);         // plane row for r=0,1; hg+1 for r=2,3
        float b0r = bias[q * BS + hg];
        float b0i = bias[768 + q * BS + hg];
        float b1r = bias[q * BS + hg + 1];
        float b1i = bias[768 + q * BS + hg + 1];
        size_t row0 = ((size_t)bq * BS + hg) * NN + mblk * 128;
        #pragma unroll
        for (int tm = 0; tm < 4; tm++) {
            int mcol = wm + tm * 16 + l15;
            f32x4 a = acc[tn][tm];
            float v0 = a[0] + b0r, v1 = a[1] + b0i;
            float v2 = a[2] + b1r, v3 = a[3] + b1i;
            if (ACT == 0) {
                v0 = fmaxf(v0, 0.f); v1 = fmaxf(v1, 0.f);
                v2 = fmaxf(v2, 0.f); v3 = fmaxf(v3, 0.f);
            } else {
                v0 = (v0 > LAM) ? (v0 - LAM) : ((v0 < -LAM) ? (v0 + LAM) : 0.f);
                v1 = (v1 > LAM) ? (v1 - LAM) : ((v1 < -LAM) ? (v1 + LAM) : 0.f);
                v2 = (v2 > LAM) ? (v2 - LAM) : ((v2 < -LAM) ? (v2 + LAM) : 0.f);
                v3 = (v3 > LAM) ? (v3 - LAM) : ((v3 < -LAM) ? (v3 + LAM) : 0.f);
            }
            Cp[row0 + mcol]      = pack2(v0, v1);
            Cp[row0 + NN + mcol] = pack2(v2, v3);
        }
    }
}

// ---------------------------------------------------------------------------
// Kernel 4: inverse q-IDFT + radix-4 DIT IFFT + residual (unchanged).
// ---------------------------------------------------------------------------
__global__ void inv_fft(const float* __restrict__ x,
                        const unsigned* __restrict__ Yp,
                        float* __restrict__ out) {
    __shared__ float2 bufs[4][1024];
    int d = blockIdx.x, b = blockIdx.y, tid = threadIdx.x;

    float Ar[4][4], Ai[4][4];
    size_t qs = (size_t)BS * NN;
    size_t rowb = (((size_t)b * 4) * BS + d) * NN + 4 * tid;
    #pragma unroll
    for (int q = 0; q < 4; q++) {
        uint4 v = *(const uint4*)(Yp + rowb + (size_t)q * qs);
        Ar[q][0] = bflo(v.x); Ai[q][0] = bfhi(v.x);
        Ar[q][1] = bflo(v.y); Ai[q][1] = bfhi(v.y);
        Ar[q][2] = bflo(v.z); Ai[q][2] = bfhi(v.z);
        Ar[q][3] = bflo(v.w); Ai[q][3] = bfhi(v.w);
    }
    #pragma unroll
    for (int m = 0; m < 4; m++) {
        float x0r = Ar[0][m], x0i = Ai[0][m];
        float x1r = Ar[1][m], x1i = Ai[1][m];
        float x2r = Ar[2][m], x2i = Ai[2][m];
        float x3r = Ar[3][m], x3i = Ai[3][m];
        float Y0r = x0r + x1r + x2r + x3r, Y0i = x0i + x1i + x2i + x3i;
        float Y2r = x0r - x1r + x2r - x3r, Y2i = x0i - x1i + x2i - x3i;
        float Y1r = x0r - x1i - x2r + x3i, Y1i = x0i + x1r - x2i - x3r;
        float Y3r = x0r + x1i - x2r - x3i, Y3i = x0i - x1r - x2i + x3r;
        Ar[0][m] = Y0r; Ai[0][m] = Y0i;
        Ar[1][m] = Y1r; Ai[1][m] = Y1i;
        Ar[2][m] = Y2r; Ai[2][m] = Y2i;
        Ar[3][m] = Y3r; Ai[3][m] = Y3i;
    }
    int i0 = swz(4 * tid);
    #pragma unroll
    for (int q = 0; q < 4; q++) {
        float t0r = Ar[q][0] + Ar[q][2], t0i = Ai[q][0] + Ai[q][2];
        float t1r = Ar[q][0] - Ar[q][2], t1i = Ai[q][0] - Ai[q][2];
        float t2r = Ar[q][1] + Ar[q][3], t2i = Ai[q][1] + Ai[q][3];
        float t3r = Ar[q][1] - Ar[q][3], t3i = Ai[q][1] - Ai[q][3];
        float4* p = (float4*)&bufs[q][i0];
        p[0] = make_float4(t0r + t2r, t0i + t2i, t1r - t3i, t1i + t3r);
        p[1] = make_float4(t0r - t2r, t0i - t2i, t1r + t3i, t1i - t3r);
    }
    __syncthreads();

    #pragma unroll
    for (int sL = 0; sL < 4; sL++) {
        const int L = 4 << (2 * sL);
        int j = tid & (L - 1);
        int base = ((tid - j) << 2) + j;
        float s1, c1;
        __sincosf((float)M_PI * 0.5f * (float)j / (float)L, &s1, &c1);
        float c2 = c1 * c1 - s1 * s1, s2 = 2.f * c1 * s1;
        float c3 = c2 * c1 - s2 * s1, s3 = c2 * s1 + s2 * c1;
        #pragma unroll
        for (int q = 0; q < 4; q++) {
            float2 y0 = bufs[q][swz(base)];
            float2 y1 = bufs[q][swz(base + L)];
            float2 y2 = bufs[q][swz(base + 2 * L)];
            float2 y3 = bufs[q][swz(base + 3 * L)];
            float A1r = y1.x * c1 - y1.y * s1, A1i = y1.x * s1 + y1.y * c1;
            float A2r = y2.x * c2 - y2.y * s2, A2i = y2.x * s2 + y2.y * c2;
            float A3r = y3.x * c3 - y3.y * s3, A3i = y3.x * s3 + y3.y * c3;
            float t0r = y0.x + A2r, t0i = y0.y + A2i;
            float t1r = y0.x - A2r, t1i = y0.y - A2i;
            float t2r = A1r + A3r, t2i = A1i + A3i;
            float t3r = A1r - A3r, t3i = A1i - A3i;
            bufs[q][swz(base)]         = make_float2(t0r + t2r, t0i + t2i);
            bufs[q][swz(base + L)]     = make_float2(t1r - t3i, t1i + t3r);
            bufs[q][swz(base + 2 * L)] = make_float2(t0r - t2r, t0i - t2i);
            bufs[q][swz(base + 3 * L)] = make_float2(t1r + t3i, t1i - t3r);
        }
        __syncthreads();
    }

    const float sc = 1.f / 64.f;
    #pragma unroll
    for (int q = 0; q < 4; q++) {
        size_t row = (((size_t)b * 4 + q) * BS + d) * NN;
        const float* xp = x + row;
        #pragma unroll
        for (int k = 0; k < 4; k++) {
            int n = tid + 256 * k;
            out[row + n] = bufs[q][swz(n)].x * sc + xp[n];
        }
    }
}

// ---------------------------------------------------------------------------
extern "C" void kernel_launch(void* const* d_in, const int* in_sizes, int n_in,
                              void* d_out, int out_size, void* d_ws, size_t ws_size,
                              hipStream_t stream) {
    const float* x     = (const float*)d_in[0];
    const float* w1    = (const float*)d_in[1];
    const float* w2    = (const float*)d_in[2];
    const float* b1    = (const float*)d_in[3];
    const float* b2    = (const float*)d_in[4];
    const float* gamma = (const float*)d_in[5];
    const float* beta  = (const float*)d_in[6];

    unsigned* Xp = (unsigned*)d_ws;
    float* mu    = (float*)d_ws + (size_t)BB * CC * NN;
    float* rstd  = mu + (size_t)BB * NN;
    unsigned* Bp1 = (unsigned*)(rstd + (size_t)BB * NN);
    unsigned* Bp2 = Bp1 + (size_t)4 * 3 * 12 * 2048;
    unsigned* Hp = (unsigned*)d_out;
    unsigned* Yp = Xp;

    pack_b<<<dim3(12, 3, 4), 256, 0, stream>>>(w1, Bp1);
    pack_b<<<dim3(12, 3, 4), 256, 0, stream>>>(w2, Bp2);
    ln_stats<<<dim3(NN / 64, BB), 256, 0, stream>>>(x, mu, rstd);
    fwd_fft<<<dim3(BS, BB), 256, 0, stream>>>(x, mu, rstd, gamma, beta, Xp);
    gemm_mlp<0><<<dim3(8, 3, 256), 256, 0, stream>>>(Xp, Bp1, b1, Hp);
    gemm_mlp<1><<<dim3(8, 3, 256), 256, 0, stream>>>(Hp, Bp2, b2, Yp);
    inv_fft<<<dim3(BS, BB), 256, 0, stream>>>(x, Yp, (float*)d_out);
}

// Round 4
// 862.930 us; speedup vs baseline: 1.9585x; 1.0027x over previous
//
#include <hip/hip_runtime.h>
#include <math.h>

#define BB 64
#define CC 768
#define NN 1024
#define BS 192
#define EPS 1e-5f
#define LAM 0.01f

typedef float  f32x4  __attribute__((ext_vector_type(4)));
typedef short  bf16x8 __attribute__((ext_vector_type(8)));

__device__ inline unsigned f2bf(float x) {
    unsigned u = __float_as_uint(x);
    u += 0x7fff + ((u >> 16) & 1);   // RNE
    return u >> 16;
}
__device__ inline unsigned pack2(float r, float i) { return f2bf(r) | (f2bf(i) << 16); }
__device__ inline float bflo(unsigned v) { return __uint_as_float(v << 16); }
__device__ inline float bfhi(unsigned v) { return __uint_as_float(v & 0xffff0000u); }

// LDS bank swizzle on float2 index (FFT kernels): XOR bits 4-5 into bits 2-3.
__device__ inline int swz(int i) { return i ^ (((i >> 4) & 3) << 2); }

// Plane-column swizzle (GEMM A-path): plane row r stores logical col n at
// n ^ ((r>>2)&3)<<3. Makes the GEMM's [d][m] LDS A-tile (staged linearly by
// global_load_lds) bank-conflict-free under the quad-XOR fragment read.
// Producers (fwd_fft, gemm epilogue) write swizzled; inv_fft unswizzles.

// ---------------------------------------------------------------------------
// Kernel 1: LayerNorm statistics per (b, n).
// ---------------------------------------------------------------------------
__global__ void ln_stats(const float* __restrict__ x,
                         float* __restrict__ mu, float* __restrict__ rstd) {
    int tn = threadIdx.x & 63, tc = threadIdx.x >> 6;
    int n = blockIdx.x * 64 + tn, b = blockIdx.y;
    const float* xp = x + (size_t)b * CC * NN + n;
    float s = 0.f, ss = 0.f;
    for (int c = tc; c < CC; c += 4) {
        float v = xp[(size_t)c * NN];
        s += v; ss += v * v;
    }
    __shared__ float sm[4][64], sq[4][64];
    sm[tc][tn] = s; sq[tc][tn] = ss;
    __syncthreads();
    if (tc == 0) {
        s  = sm[0][tn] + sm[1][tn] + sm[2][tn] + sm[3][tn];
        ss = sq[0][tn] + sq[1][tn] + sq[2][tn] + sq[3][tn];
        float m = s * (1.f / 768.f);
        float v = ss * (1.f / 768.f) - m * m;
        mu[b * NN + n] = m;
        rstd[b * NN + n] = rsqrtf(v + EPS);
    }
}

// ---------------------------------------------------------------------------
// Kernel 2: LN-apply + 1024-pt radix-4 DIF FFT (n) + 4-pt DFT (q) + 1/64.
// Stores plane rows with the column swizzle (n ^ ((d>>2)&3)<<3).
// ---------------------------------------------------------------------------
__global__ void fwd_fft(const float* __restrict__ x,
                        const float* __restrict__ mu_, const float* __restrict__ rs_,
                        const float* __restrict__ gamma, const float* __restrict__ beta,
                        unsigned* __restrict__ Xp) {
    __shared__ float2 bufs[4][1024];
    int d = blockIdx.x, b = blockIdx.y, tid = threadIdx.x;

    const float* mp = mu_ + b * NN;
    const float* rp = rs_ + b * NN;
    #pragma unroll
    for (int q = 0; q < 4; q++) {
        int c = q * BS + d;
        float g = gamma[c], be = beta[c];
        const float* xp = x + ((size_t)b * CC + c) * NN;
        #pragma unroll
        for (int k = 0; k < 4; k++) {
            int n = tid + 256 * k;
            float v = (xp[n] - mp[n]) * rp[n] * g + be;
            bufs[q][swz(n)] = make_float2(v, 0.f);
        }
    }
    __syncthreads();

    #pragma unroll
    for (int sL = 0; sL < 4; sL++) {
        const int L = 256 >> (2 * sL);
        int j = tid & (L - 1);
        int base = ((tid - j) << 2) + j;
        float s1, c1;
        __sincosf(-(float)M_PI * 0.5f * (float)j / (float)L, &s1, &c1);
        float c2 = c1 * c1 - s1 * s1, s2 = 2.f * c1 * s1;
        float c3 = c2 * c1 - s2 * s1, s3 = c2 * s1 + s2 * c1;
        #pragma unroll
        for (int q = 0; q < 4; q++) {
            float2 a  = bufs[q][swz(base)];
            float2 bb = bufs[q][swz(base + L)];
            float2 cc = bufs[q][swz(base + 2 * L)];
            float2 dd = bufs[q][swz(base + 3 * L)];
            float t0r = a.x + cc.x, t0i = a.y + cc.y;
            float t1r = a.x - cc.x, t1i = a.y - cc.y;
            float t2r = bb.x + dd.x, t2i = bb.y + dd.y;
            float t3r = bb.x - dd.x, t3i = bb.y - dd.y;
            float X0r = t0r + t2r, X0i = t0i + t2i;
            float X2r = t0r - t2r, X2i = t0i - t2i;
            float X1r = t1r + t3i, X1i = t1i - t3r;
            float X3r = t1r - t3i, X3i = t1i + t3r;
            bufs[q][swz(base)]         = make_float2(X0r, X0i);
            bufs[q][swz(base + L)]     = make_float2(X1r * c1 - X1i * s1, X1r * s1 + X1i * c1);
            bufs[q][swz(base + 2 * L)] = make_float2(X2r * c2 - X2i * s2, X2r * s2 + X2i * c2);
            bufs[q][swz(base + 3 * L)] = make_float2(X3r * c3 - X3i * s3, X3r * s3 + X3i * c3);
        }
        __syncthreads();
    }

    float Xr[4][4], Xi[4][4];
    int i0 = swz(4 * tid);
    #pragma unroll
    for (int q = 0; q < 4; q++) {
        const float4* p = (const float4*)&bufs[q][i0];
        float4 u0 = p[0], u1 = p[1];
        float t0r = u0.x + u1.x, t0i = u0.y + u1.y;
        float t1r = u0.x - u1.x, t1i = u0.y - u1.y;
        float t2r = u0.z + u1.z, t2i = u0.w + u1.w;
        float t3r = u0.z - u1.z, t3i = u0.w - u1.w;
        Xr[q][0] = t0r + t2r; Xi[q][0] = t0i + t2i;
        Xr[q][1] = t1r + t3i; Xi[q][1] = t1i - t3r;
        Xr[q][2] = t0r - t2r; Xi[q][2] = t0i - t2i;
        Xr[q][3] = t1r - t3i; Xi[q][3] = t1i + t3r;
    }
    const float sc = 1.f / 64.f;
    unsigned o0[4], o1[4], o2[4], o3[4];
    #pragma unroll
    for (int m = 0; m < 4; m++) {
        float x0r = Xr[0][m], x0i = Xi[0][m];
        float x1r = Xr[1][m], x1i = Xi[1][m];
        float x2r = Xr[2][m], x2i = Xi[2][m];
        float x3r = Xr[3][m], x3i = Xi[3][m];
        float X0r = x0r + x1r + x2r + x3r, X0i = x0i + x1i + x2i + x3i;
        float X2r = x0r - x1r + x2r - x3r, X2i = x0i - x1i + x2i - x3i;
        float X1r = x0r + x1i - x2r - x3i, X1i = x0i - x1r - x2i + x3r;
        float X3r = x0r - x1i - x2r + x3i, X3i = x0i + x1r - x2i - x3r;
        o0[m] = pack2(X0r * sc, X0i * sc);
        o1[m] = pack2(X1r * sc, X1i * sc);
        o2[m] = pack2(X2r * sc, X2i * sc);
        o3[m] = pack2(X3r * sc, X3i * sc);
    }
    size_t qs = (size_t)BS * NN;
    int cs = ((d >> 2) & 3) << 3;    // plane-column swizzle for row d
    size_t base = (((size_t)b * 4) * BS + d) * NN + ((4 * tid) ^ cs);
    *(uint4*)(Xp + base)          = make_uint4(o0[0], o0[1], o0[2], o0[3]);
    *(uint4*)(Xp + base + qs)     = make_uint4(o1[0], o1[1], o1[2], o1[3]);
    *(uint4*)(Xp + base + 2 * qs) = make_uint4(o2[0], o2[1], o2[2], o2[3]);
    *(uint4*)(Xp + base + 3 * qs) = make_uint4(o3[0], o3[1], o3[2], o3[3]);
}

// ---------------------------------------------------------------------------
// Kernel 2b: one-time B prepack (unchanged layout).
// ---------------------------------------------------------------------------
__global__ void pack_b(const float* __restrict__ w, unsigned* __restrict__ Bp) {
    int ch = blockIdx.x, nblk = blockIdx.y, q = blockIdx.z;
    size_t tile = (size_t)((q * 3 + nblk) * 12 + ch);
    const float* wr = w + (size_t)q * BS * BS;
    const float* wi = w + (size_t)(4 + q) * BS * BS;
    for (int r = 0; r < 8; r++) {
        int idx = r * 256 + threadIdx.x;
        int jl = idx & 127, dd = idx >> 7;
        int j = nblk * 128 + jl;
        int h = j >> 1;
        int dg = ch * 16 + dd;
        float Wr = wr[(size_t)dg * BS + h];
        float Wi = wi[(size_t)dg * BS + h];
        unsigned v = (j & 1) ? pack2(Wi, Wr) : pack2(Wr, -Wi);
        int col = ((dd >> 2) ^ ((jl >> 1) & 3)) * 4 + (dd & 3);
        Bp[tile * 2048 + jl * 16 + col] = v;
    }
}

// ---------------------------------------------------------------------------
// Kernel 3: bf16 MFMA GEMM, fully dma-staged + counted-vmcnt pipeline (T3/T4).
// A: [16 d-rows][128 m] per chunk, staged linearly by global_load_lds from
//    column-swizzled planes; frag read = 4x ds_read_b32 with quad-XOR (2-way).
// B: prepacked swizzled tiles, staged by global_load_lds (as before).
// Triple-buffered, depth-2 prefetch, s_waitcnt vmcnt(4) per chunk (never 0
// mid-loop). One s_barrier per chunk. Operand-swapped MFMA, register epilogue.
// ---------------------------------------------------------------------------
template <int ACT>
__global__ __launch_bounds__(256) void gemm_mlp(const unsigned* __restrict__ Ap,
                                                const unsigned* __restrict__ Bp,
                                                const float* __restrict__ bias,
                                                unsigned* __restrict__ Cp) {
    __shared__ unsigned sa[3][2048];   // [buf][d=16][m=128]
    __shared__ unsigned sb[3][2048];   // [buf][j=128][kcol=16]

    const int mblk = blockIdx.x;
    const int nblk = blockIdx.y;
    const int bq   = blockIdx.z;
    const int q    = bq & 3;
    const int tid  = threadIdx.x;
    const int wave = tid >> 6;
    const int lane = tid & 63;
    const int l15  = lane & 15;
    const int quad = lane >> 4;
    const int wm   = (wave & 1) * 64;
    const int wn   = (wave >> 1) * 64;

    const unsigned* a_base = Ap + ((size_t)bq * BS) * NN + mblk * 128;
    const size_t a_lane = (size_t)(lane >> 5) * NN + (lane & 31) * 4;
    const unsigned* b_tiles = Bp + (size_t)((q * 3 + nblk) * 12) * 2048;
    const int fgrp = (quad ^ ((l15 >> 1) & 3)) * 16;
    const int r0 = wave * 4;           // A d-rows staged by this wave

    f32x4 acc[4][4];   // acc[tn][tm]
    #pragma unroll
    for (int i = 0; i < 4; i++)
        #pragma unroll
        for (int j = 0; j < 4; j++)
            acc[i][j] = (f32x4)0.f;

    // stage chunk ch into buffer buf: 4 dma per wave (2 A rows-pairs + 2 B)
    auto STAGE = [&](int ch, int buf) {
        const unsigned* ga = a_base + (size_t)(ch * 16) * NN;
        __builtin_amdgcn_global_load_lds(
            (const __attribute__((address_space(1))) unsigned*)(ga + (size_t)r0 * NN + a_lane),
            (__attribute__((address_space(3))) unsigned*)(&sa[buf][r0 * 128]), 16, 0, 0);
        __builtin_amdgcn_global_load_lds(
            (const __attribute__((address_space(1))) unsigned*)(ga + (size_t)(r0 + 2) * NN + a_lane),
            (__attribute__((address_space(3))) unsigned*)(&sa[buf][(r0 + 2) * 128]), 16, 0, 0);
        const unsigned* gb = b_tiles + (size_t)ch * 2048 + wave * 512;
        __builtin_amdgcn_global_load_lds(
            (const __attribute__((address_space(1))) unsigned*)(gb + lane * 4),
            (__attribute__((address_space(3))) unsigned*)(&sb[buf][wave * 512]), 16, 0, 0);
        __builtin_amdgcn_global_load_lds(
            (const __attribute__((address_space(1))) unsigned*)(gb + 256 + lane * 4),
            (__attribute__((address_space(3))) unsigned*)(&sb[buf][wave * 512 + 256]), 16, 0, 0);
    };

    STAGE(0, 0);
    STAGE(1, 1);

    #pragma unroll
    for (int ch = 0; ch < 12; ch++) {
        const int buf = ch % 3;
        // wait for THIS wave's chunk-ch dmas (4 newest may stay in flight);
        // barrier then publishes all waves' completions.
        if (ch < 11) asm volatile("s_waitcnt vmcnt(4)" ::: "memory");
        else         asm volatile("s_waitcnt vmcnt(0)" ::: "memory");
        __builtin_amdgcn_sched_barrier(0);
        __builtin_amdgcn_s_barrier();
        __builtin_amdgcn_sched_barrier(0);
        if (ch < 10) STAGE(ch + 2, (ch + 2) % 3);

        bf16x8 af[4], bfr[4];
        const unsigned* sap = sa[buf];
        #pragma unroll
        for (int t = 0; t < 4; t++) {
            int cx = (wm + t * 16 + l15) ^ (quad << 3);
            union { unsigned u[4]; bf16x8 v; } au;
            #pragma unroll
            for (int g = 0; g < 4; g++)
                au.u[g] = sap[(quad * 4 + g) * 128 + cx];
            af[t] = au.v;
            bfr[t] = *(const bf16x8*)((const char*)sb[buf] + (wn + t * 16 + l15) * 64 + fgrp);
        }
        #pragma unroll
        for (int tn = 0; tn < 4; tn++)
            #pragma unroll
            for (int tm = 0; tm < 4; tm++)
                acc[tn][tm] = __builtin_amdgcn_mfma_f32_16x16x32_bf16(bfr[tn], af[tm], acc[tn][tm], 0, 0, 0);
    }

    // epilogue: bias + act + pack in registers; stores use the plane-column
    // swizzle (consumer = next gemm's A-stage or inv_fft).
    #pragma unroll
    for (int tn = 0; tn < 4; tn++) {
        int jb = wn + tn * 16 + quad * 4;
        int hg = nblk * 64 + (jb >> 1);
        float b0r = bias[q * BS + hg];
        float b0i = bias[768 + q * BS + hg];
        float b1r = bias[q * BS + hg + 1];
        float b1i = bias[768 + q * BS + hg + 1];
        int s0 = ((hg >> 2) & 3) << 3;
        int s1 = (((hg + 1) >> 2) & 3) << 3;
        size_t row0 = ((size_t)bq * BS + hg) * NN + mblk * 128;
        #pragma unroll
        for (int tm = 0; tm < 4; tm++) {
            int mcol = wm + tm * 16 + l15;
            f32x4 a = acc[tn][tm];
            float v0 = a[0] + b0r, v1 = a[1] + b0i;
            float v2 = a[2] + b1r, v3 = a[3] + b1i;
            if (ACT == 0) {
                v0 = fmaxf(v0, 0.f); v1 = fmaxf(v1, 0.f);
                v2 = fmaxf(v2, 0.f); v3 = fmaxf(v3, 0.f);
            } else {
                v0 = (v0 > LAM) ? (v0 - LAM) : ((v0 < -LAM) ? (v0 + LAM) : 0.f);
                v1 = (v1 > LAM) ? (v1 - LAM) : ((v1 < -LAM) ? (v1 + LAM) : 0.f);
                v2 = (v2 > LAM) ? (v2 - LAM) : ((v2 < -LAM) ? (v2 + LAM) : 0.f);
                v3 = (v3 > LAM) ? (v3 - LAM) : ((v3 < -LAM) ? (v3 + LAM) : 0.f);
            }
            Cp[row0 + (mcol ^ s0)]      = pack2(v0, v1);
            Cp[row0 + NN + (mcol ^ s1)] = pack2(v2, v3);
        }
    }
}

// ---------------------------------------------------------------------------
// Kernel 4: inverse q-IDFT + radix-4 DIT IFFT + residual. Un-swizzles the
// plane columns on load (uniform per block -> coalescing preserved).
// ---------------------------------------------------------------------------
__global__ void inv_fft(const float* __restrict__ x,
                        const unsigned* __restrict__ Yp,
                        float* __restrict__ out) {
    __shared__ float2 bufs[4][1024];
    int d = blockIdx.x, b = blockIdx.y, tid = threadIdx.x;

    float Ar[4][4], Ai[4][4];
    size_t qs = (size_t)BS * NN;
    int cs = ((d >> 2) & 3) << 3;
    size_t rowb = (((size_t)b * 4) * BS + d) * NN + ((4 * tid) ^ cs);
    #pragma unroll
    for (int q = 0; q < 4; q++) {
        uint4 v = *(const uint4*)(Yp + rowb + (size_t)q * qs);
        Ar[q][0] = bflo(v.x); Ai[q][0] = bfhi(v.x);
        Ar[q][1] = bflo(v.y); Ai[q][1] = bfhi(v.y);
        Ar[q][2] = bflo(v.z); Ai[q][2] = bfhi(v.z);
        Ar[q][3] = bflo(v.w); Ai[q][3] = bfhi(v.w);
    }
    #pragma unroll
    for (int m = 0; m < 4; m++) {
        float x0r = Ar[0][m], x0i = Ai[0][m];
        float x1r = Ar[1][m], x1i = Ai[1][m];
        float x2r = Ar[2][m], x2i = Ai[2][m];
        float x3r = Ar[3][m], x3i = Ai[3][m];
        float Y0r = x0r + x1r + x2r + x3r, Y0i = x0i + x1i + x2i + x3i;
        float Y2r = x0r - x1r + x2r - x3r, Y2i = x0i - x1i + x2i - x3i;
        float Y1r = x0r - x1i - x2r + x3i, Y1i = x0i + x1r - x2i - x3r;
        float Y3r = x0r + x1i - x2r - x3i, Y3i = x0i - x1r - x2i + x3r;
        Ar[0][m] = Y0r; Ai[0][m] = Y0i;
        Ar[1][m] = Y1r; Ai[1][m] = Y1i;
        Ar[2][m] = Y2r; Ai[2][m] = Y2i;
        Ar[3][m] = Y3r; Ai[3][m] = Y3i;
    }
    int i0 = swz(4 * tid);
    #pragma unroll
    for (int q = 0; q < 4; q++) {
        float t0r = Ar[q][0] + Ar[q][2], t0i = Ai[q][0] + Ai[q][2];
        float t1r = Ar[q][0] - Ar[q][2], t1i = Ai[q][0] - Ai[q][2];
        float t2r = Ar[q][1] + Ar[q][3], t2i = Ai[q][1] + Ai[q][3];
        float t3r = Ar[q][1] - Ar[q][3], t3i = Ai[q][1] - Ai[q][3];
        float4* p = (float4*)&bufs[q][i0];
        p[0] = make_float4(t0r + t2r, t0i + t2i, t1r - t3i, t1i + t3r);
        p[1] = make_float4(t0r - t2r, t0i - t2i, t1r + t3i, t1i - t3r);
    }
    __syncthreads();

    #pragma unroll
    for (int sL = 0; sL < 4; sL++) {
        const int L = 4 << (2 * sL);
        int j = tid & (L - 1);
        int base = ((tid - j) << 2) + j;
        float s1, c1;
        __sincosf((float)M_PI * 0.5f * (float)j / (float)L, &s1, &c1);
        float c2 = c1 * c1 - s1 * s1, s2 = 2.f * c1 * s1;
        float c3 = c2 * c1 - s2 * s1, s3 = c2 * s1 + s2 * c1;
        #pragma unroll
        for (int q = 0; q < 4; q++) {
            float2 y0 = bufs[q][swz(base)];
            float2 y1 = bufs[q][swz(base + L)];
            float2 y2 = bufs[q][swz(base + 2 * L)];
            float2 y3 = bufs[q][swz(base + 3 * L)];
            float A1r = y1.x * c1 - y1.y * s1, A1i = y1.x * s1 + y1.y * c1;
            float A2r = y2.x * c2 - y2.y * s2, A2i = y2.x * s2 + y2.y * c2;
            float A3r = y3.x * c3 - y3.y * s3, A3i = y3.x * s3 + y3.y * c3;
            float t0r = y0.x + A2r, t0i = y0.y + A2i;
            float t1r = y0.x - A2r, t1i = y0.y - A2i;
            float t2r = A1r + A3r, t2i = A1i + A3i;
            float t3r = A1r - A3r, t3i = A1i - A3i;
            bufs[q][swz(base)]         = make_float2(t0r + t2r, t0i + t2i);
            bufs[q][swz(base + L)]     = make_float2(t1r - t3i, t1i + t3r);
            bufs[q][swz(base + 2 * L)] = make_float2(t0r - t2r, t0i - t2i);
            bufs[q][swz(base + 3 * L)] = make_float2(t1r + t3i, t1i - t3r);
        }
        __syncthreads();
    }

    const float sc = 1.f / 64.f;
    #pragma unroll
    for (int q = 0; q < 4; q++) {
        size_t row = (((size_t)b * 4 + q) * BS + d) * NN;
        const float* xp = x + row;
        #pragma unroll
        for (int k = 0; k < 4; k++) {
            int n = tid + 256 * k;
            out[row + n] = bufs[q][swz(n)].x * sc + xp[n];
        }
    }
}

// ---------------------------------------------------------------------------
extern "C" void kernel_launch(void* const* d_in, const int* in_sizes, int n_in,
                              void* d_out, int out_size, void* d_ws, size_t ws_size,
                              hipStream_t stream) {
    const float* x     = (const float*)d_in[0];
    const float* w1    = (const float*)d_in[1];
    const float* w2    = (const float*)d_in[2];
    const float* b1    = (const float*)d_in[3];
    const float* b2    = (const float*)d_in[4];
    const float* gamma = (const float*)d_in[5];
    const float* beta  = (const float*)d_in[6];

    unsigned* Xp = (unsigned*)d_ws;
    float* mu    = (float*)d_ws + (size_t)BB * CC * NN;
    float* rstd  = mu + (size_t)BB * NN;
    unsigned* Bp1 = (unsigned*)(rstd + (size_t)BB * NN);
    unsigned* Bp2 = Bp1 + (size_t)4 * 3 * 12 * 2048;
    unsigned* Hp = (unsigned*)d_out;
    unsigned* Yp = Xp;

    pack_b<<<dim3(12, 3, 4), 256, 0, stream>>>(w1, Bp1);
    pack_b<<<dim3(12, 3, 4), 256, 0, stream>>>(w2, Bp2);
    ln_stats<<<dim3(NN / 64, BB), 256, 0, stream>>>(x, mu, rstd);
    fwd_fft<<<dim3(BS, BB), 256, 0, stream>>>(x, mu, rstd, gamma, beta, Xp);
    gemm_mlp<0><<<dim3(8, 3, 256), 256, 0, stream>>>(Xp, Bp1, b1, Hp);
    gemm_mlp<1><<<dim3(8, 3, 256), 256, 0, stream>>>(Hp, Bp2, b2, Yp);
    inv_fft<<<dim3(BS, BB), 256, 0, stream>>>(x, Yp, (float*)d_out);
}

// Round 5
// 798.563 us; speedup vs baseline: 2.1164x; 1.0806x over previous
//
#include <hip/hip_runtime.h>
#include <math.h>

#define BB 64
#define CC 768
#define NN 1024
#define BS 192
#define EPS 1e-5f
#define LAM 0.01f

typedef float  f32x4  __attribute__((ext_vector_type(4)));
typedef short  bf16x8 __attribute__((ext_vector_type(8)));

__device__ inline unsigned f2bf(float x) {
    unsigned u = __float_as_uint(x);
    u += 0x7fff + ((u >> 16) & 1);   // RNE
    return u >> 16;
}
__device__ inline unsigned pack2(float r, float i) { return f2bf(r) | (f2bf(i) << 16); }
__device__ inline float bflo(unsigned v) { return __uint_as_float(v << 16); }
__device__ inline float bfhi(unsigned v) { return __uint_as_float(v & 0xffff0000u); }

// LDS bank swizzle on float2 index (FFT kernels): XOR bits 4-5 into bits 2-3.
__device__ inline int swz(int i) { return i ^ (((i >> 4) & 3) << 2); }

// ---------------------------------------------------------------------------
// Kernel 1: LayerNorm statistics per (b, n). float4-vectorized along n.
// ---------------------------------------------------------------------------
__global__ __launch_bounds__(512) void ln_stats(const float* __restrict__ x,
                                                float* __restrict__ mu,
                                                float* __restrict__ rstd) {
    int tn = threadIdx.x & 63, tc = threadIdx.x >> 6;   // tc: 0..7
    int n = blockIdx.x * 256 + tn * 4, b = blockIdx.y;
    const float* xp = x + (size_t)b * CC * NN + n;
    f32x4 s = (f32x4)0.f, ss = (f32x4)0.f;
    #pragma unroll 4
    for (int c = tc; c < CC; c += 8) {
        f32x4 v = *(const f32x4*)(xp + (size_t)c * NN);
        s += v; ss += v * v;
    }
    __shared__ f32x4 sm[8][64], sq[8][64];
    sm[tc][tn] = s; sq[tc][tn] = ss;
    __syncthreads();
    if (tc == 0) {
        f32x4 S  = sm[0][tn], SS = sq[0][tn];
        #pragma unroll
        for (int i = 1; i < 8; i++) { S += sm[i][tn]; SS += sq[i][tn]; }
        f32x4 m = S * (1.f / 768.f);
        f32x4 r;
        #pragma unroll
        for (int i = 0; i < 4; i++) {
            float var = SS[i] * (1.f / 768.f) - m[i] * m[i];
            r[i] = rsqrtf(var + EPS);
        }
        *(f32x4*)(mu + (size_t)b * NN + n)   = m;
        *(f32x4*)(rstd + (size_t)b * NN + n) = r;
    }
}

// ---------------------------------------------------------------------------
// Kernel 2: LN-apply + 1024-pt radix-4 DIF FFT (n) + 4-pt DFT (q) + 1/64.
// Stores plane rows with the column swizzle (n ^ ((d>>2)&3)<<3).
// ---------------------------------------------------------------------------
__global__ void fwd_fft(const float* __restrict__ x,
                        const float* __restrict__ mu_, const float* __restrict__ rs_,
                        const float* __restrict__ gamma, const float* __restrict__ beta,
                        unsigned* __restrict__ Xp) {
    __shared__ float2 bufs[4][1024];
    int d = blockIdx.x, b = blockIdx.y, tid = threadIdx.x;

    const float* mp = mu_ + b * NN;
    const float* rp = rs_ + b * NN;
    #pragma unroll
    for (int q = 0; q < 4; q++) {
        int c = q * BS + d;
        float g = gamma[c], be = beta[c];
        const float* xp = x + ((size_t)b * CC + c) * NN;
        #pragma unroll
        for (int k = 0; k < 4; k++) {
            int n = tid + 256 * k;
            float v = (xp[n] - mp[n]) * rp[n] * g + be;
            bufs[q][swz(n)] = make_float2(v, 0.f);
        }
    }
    __syncthreads();

    #pragma unroll
    for (int sL = 0; sL < 4; sL++) {
        const int L = 256 >> (2 * sL);
        int j = tid & (L - 1);
        int base = ((tid - j) << 2) + j;
        float s1, c1;
        __sincosf(-(float)M_PI * 0.5f * (float)j / (float)L, &s1, &c1);
        float c2 = c1 * c1 - s1 * s1, s2 = 2.f * c1 * s1;
        float c3 = c2 * c1 - s2 * s1, s3 = c2 * s1 + s2 * c1;
        #pragma unroll
        for (int q = 0; q < 4; q++) {
            float2 a  = bufs[q][swz(base)];
            float2 bb = bufs[q][swz(base + L)];
            float2 cc = bufs[q][swz(base + 2 * L)];
            float2 dd = bufs[q][swz(base + 3 * L)];
            float t0r = a.x + cc.x, t0i = a.y + cc.y;
            float t1r = a.x - cc.x, t1i = a.y - cc.y;
            float t2r = bb.x + dd.x, t2i = bb.y + dd.y;
            float t3r = bb.x - dd.x, t3i = bb.y - dd.y;
            float X0r = t0r + t2r, X0i = t0i + t2i;
            float X2r = t0r - t2r, X2i = t0i - t2i;
            float X1r = t1r + t3i, X1i = t1i - t3r;
            float X3r = t1r - t3i, X3i = t1i + t3r;
            bufs[q][swz(base)]         = make_float2(X0r, X0i);
            bufs[q][swz(base + L)]     = make_float2(X1r * c1 - X1i * s1, X1r * s1 + X1i * c1);
            bufs[q][swz(base + 2 * L)] = make_float2(X2r * c2 - X2i * s2, X2r * s2 + X2i * c2);
            bufs[q][swz(base + 3 * L)] = make_float2(X3r * c3 - X3i * s3, X3r * s3 + X3i * c3);
        }
        __syncthreads();
    }

    float Xr[4][4], Xi[4][4];
    int i0 = swz(4 * tid);
    #pragma unroll
    for (int q = 0; q < 4; q++) {
        const float4* p = (const float4*)&bufs[q][i0];
        float4 u0 = p[0], u1 = p[1];
        float t0r = u0.x + u1.x, t0i = u0.y + u1.y;
        float t1r = u0.x - u1.x, t1i = u0.y - u1.y;
        float t2r = u0.z + u1.z, t2i = u0.w + u1.w;
        float t3r = u0.z - u1.z, t3i = u0.w - u1.w;
        Xr[q][0] = t0r + t2r; Xi[q][0] = t0i + t2i;
        Xr[q][1] = t1r + t3i; Xi[q][1] = t1i - t3r;
        Xr[q][2] = t0r - t2r; Xi[q][2] = t0i - t2i;
        Xr[q][3] = t1r - t3i; Xi[q][3] = t1i + t3r;
    }
    const float sc = 1.f / 64.f;
    unsigned o0[4], o1[4], o2[4], o3[4];
    #pragma unroll
    for (int m = 0; m < 4; m++) {
        float x0r = Xr[0][m], x0i = Xi[0][m];
        float x1r = Xr[1][m], x1i = Xi[1][m];
        float x2r = Xr[2][m], x2i = Xi[2][m];
        float x3r = Xr[3][m], x3i = Xi[3][m];
        float X0r = x0r + x1r + x2r + x3r, X0i = x0i + x1i + x2i + x3i;
        float X2r = x0r - x1r + x2r - x3r, X2i = x0i - x1i + x2i - x3i;
        float X1r = x0r + x1i - x2r - x3i, X1i = x0i - x1r - x2i + x3r;
        float X3r = x0r - x1i - x2r + x3i, X3i = x0i + x1r - x2i - x3r;
        o0[m] = pack2(X0r * sc, X0i * sc);
        o1[m] = pack2(X1r * sc, X1i * sc);
        o2[m] = pack2(X2r * sc, X2i * sc);
        o3[m] = pack2(X3r * sc, X3i * sc);
    }
    size_t qs = (size_t)BS * NN;
    int cs = ((d >> 2) & 3) << 3;    // plane-column swizzle for row d
    size_t base = (((size_t)b * 4) * BS + d) * NN + ((4 * tid) ^ cs);
    *(uint4*)(Xp + base)          = make_uint4(o0[0], o0[1], o0[2], o0[3]);
    *(uint4*)(Xp + base + qs)     = make_uint4(o1[0], o1[1], o1[2], o1[3]);
    *(uint4*)(Xp + base + 2 * qs) = make_uint4(o2[0], o2[1], o2[2], o2[3]);
    *(uint4*)(Xp + base + 3 * qs) = make_uint4(o3[0], o3[1], o3[2], o3[3]);
}

// ---------------------------------------------------------------------------
// Kernel 2b: one-time B prepack (unchanged layout).
// ---------------------------------------------------------------------------
__global__ void pack_b(const float* __restrict__ w, unsigned* __restrict__ Bp) {
    int ch = blockIdx.x, nblk = blockIdx.y, q = blockIdx.z;
    size_t tile = (size_t)((q * 3 + nblk) * 12 + ch);
    const float* wr = w + (size_t)q * BS * BS;
    const float* wi = w + (size_t)(4 + q) * BS * BS;
    for (int r = 0; r < 8; r++) {
        int idx = r * 256 + threadIdx.x;
        int jl = idx & 127, dd = idx >> 7;
        int j = nblk * 128 + jl;
        int h = j >> 1;
        int dg = ch * 16 + dd;
        float Wr = wr[(size_t)dg * BS + h];
        float Wi = wi[(size_t)dg * BS + h];
        unsigned v = (j & 1) ? pack2(Wi, Wr) : pack2(Wr, -Wi);
        int col = ((dd >> 2) ^ ((jl >> 1) & 3)) * 4 + (dd & 3);
        Bp[tile * 2048 + jl * 16 + col] = v;
    }
}

// ---------------------------------------------------------------------------
// Kernel 3: bf16 MFMA GEMM, dma-staged, 2-buffer depth-1 pipeline.
// LDS = 32 KB -> 5 blocks/CU (20 waves) for TLP latency hiding; the
// vmcnt(0)+barrier drain in __syncthreads is covered by other blocks.
// A: [16 d-rows][128 m] per chunk, staged linearly by global_load_lds from
//    column-swizzled planes; frag read = 4x ds_read_b32 with quad-XOR (2-way).
// B: prepacked swizzled tiles, staged by global_load_lds.
// Operand-swapped MFMA, register epilogue with direct packed stores.
// ---------------------------------------------------------------------------
template <int ACT>
__global__ __launch_bounds__(256) void gemm_mlp(const unsigned* __restrict__ Ap,
                                                const unsigned* __restrict__ Bp,
                                                const float* __restrict__ bias,
                                                unsigned* __restrict__ Cp) {
    __shared__ unsigned sa[2][2048];   // [buf][d=16][m=128]
    __shared__ unsigned sb[2][2048];   // [buf][j=128][kcol=16]

    const int mblk = blockIdx.x;
    const int nblk = blockIdx.y;
    const int bq   = blockIdx.z;
    const int q    = bq & 3;
    const int tid  = threadIdx.x;
    const int wave = tid >> 6;
    const int lane = tid & 63;
    const int l15  = lane & 15;
    const int quad = lane >> 4;
    const int wm   = (wave & 1) * 64;
    const int wn   = (wave >> 1) * 64;

    const unsigned* a_base = Ap + ((size_t)bq * BS) * NN + mblk * 128;
    const size_t a_lane = (size_t)(lane >> 5) * NN + (lane & 31) * 4;
    const unsigned* b_tiles = Bp + (size_t)((q * 3 + nblk) * 12) * 2048;
    const int fgrp = (quad ^ ((l15 >> 1) & 3)) * 16;
    const int r0 = wave * 4;           // A d-rows staged by this wave

    f32x4 acc[4][4];   // acc[tn][tm]
    #pragma unroll
    for (int i = 0; i < 4; i++)
        #pragma unroll
        for (int j = 0; j < 4; j++)
            acc[i][j] = (f32x4)0.f;

    // stage chunk ch into buffer buf: 4 dma per wave (2 A row-pairs + 2 B)
    auto STAGE = [&](int ch, int buf) {
        const unsigned* ga = a_base + (size_t)(ch * 16) * NN;
        __builtin_amdgcn_global_load_lds(
            (const __attribute__((address_space(1))) unsigned*)(ga + (size_t)r0 * NN + a_lane),
            (__attribute__((address_space(3))) unsigned*)(&sa[buf][r0 * 128]), 16, 0, 0);
        __builtin_amdgcn_global_load_lds(
            (const __attribute__((address_space(1))) unsigned*)(ga + (size_t)(r0 + 2) * NN + a_lane),
            (__attribute__((address_space(3))) unsigned*)(&sa[buf][(r0 + 2) * 128]), 16, 0, 0);
        const unsigned* gb = b_tiles + (size_t)ch * 2048 + wave * 512;
        __builtin_amdgcn_global_load_lds(
            (const __attribute__((address_space(1))) unsigned*)(gb + lane * 4),
            (__attribute__((address_space(3))) unsigned*)(&sb[buf][wave * 512]), 16, 0, 0);
        __builtin_amdgcn_global_load_lds(
            (const __attribute__((address_space(1))) unsigned*)(gb + 256 + lane * 4),
            (__attribute__((address_space(3))) unsigned*)(&sb[buf][wave * 512 + 256]), 16, 0, 0);
    };

    STAGE(0, 0);

    #pragma unroll
    for (int ch = 0; ch < 12; ch++) {
        const int buf = ch & 1;
        // drains this wave's dmas (vmcnt 0) and publishes all waves' staging;
        // also licenses overwrite of buf^1 (its readers finished last iter).
        __syncthreads();
        if (ch < 11) STAGE(ch + 1, buf ^ 1);

        bf16x8 af[4], bfr[4];
        const unsigned* sap = sa[buf];
        #pragma unroll
        for (int t = 0; t < 4; t++) {
            int cx = (wm + t * 16 + l15) ^ (quad << 3);
            union { unsigned u[4]; bf16x8 v; } au;
            #pragma unroll
            for (int g = 0; g < 4; g++)
                au.u[g] = sap[(quad * 4 + g) * 128 + cx];
            af[t] = au.v;
            bfr[t] = *(const bf16x8*)((const char*)sb[buf] + (wn + t * 16 + l15) * 64 + fgrp);
        }
        #pragma unroll
        for (int tn = 0; tn < 4; tn++)
            #pragma unroll
            for (int tm = 0; tm < 4; tm++)
                acc[tn][tm] = __builtin_amdgcn_mfma_f32_16x16x32_bf16(bfr[tn], af[tm], acc[tn][tm], 0, 0, 0);
    }

    // epilogue: bias + act + pack in registers; stores use the plane-column
    // swizzle (consumer = next gemm's A-stage or inv_fft).
    #pragma unroll
    for (int tn = 0; tn < 4; tn++) {
        int jb = wn + tn * 16 + quad * 4;
        int hg = nblk * 64 + (jb >> 1);
        float b0r = bias[q * BS + hg];
        float b0i = bias[768 + q * BS + hg];
        float b1r = bias[q * BS + hg + 1];
        float b1i = bias[768 + q * BS + hg + 1];
        int s0 = ((hg >> 2) & 3) << 3;
        int s1 = (((hg + 1) >> 2) & 3) << 3;
        size_t row0 = ((size_t)bq * BS + hg) * NN + mblk * 128;
        #pragma unroll
        for (int tm = 0; tm < 4; tm++) {
            int mcol = wm + tm * 16 + l15;
            f32x4 a = acc[tn][tm];
            float v0 = a[0] + b0r, v1 = a[1] + b0i;
            float v2 = a[2] + b1r, v3 = a[3] + b1i;
            if (ACT == 0) {
                v0 = fmaxf(v0, 0.f); v1 = fmaxf(v1, 0.f);
                v2 = fmaxf(v2, 0.f); v3 = fmaxf(v3, 0.f);
            } else {
                v0 = (v0 > LAM) ? (v0 - LAM) : ((v0 < -LAM) ? (v0 + LAM) : 0.f);
                v1 = (v1 > LAM) ? (v1 - LAM) : ((v1 < -LAM) ? (v1 + LAM) : 0.f);
                v2 = (v2 > LAM) ? (v2 - LAM) : ((v2 < -LAM) ? (v2 + LAM) : 0.f);
                v3 = (v3 > LAM) ? (v3 - LAM) : ((v3 < -LAM) ? (v3 + LAM) : 0.f);
            }
            Cp[row0 + (mcol ^ s0)]      = pack2(v0, v1);
            Cp[row0 + NN + (mcol ^ s1)] = pack2(v2, v3);
        }
    }
}

// ---------------------------------------------------------------------------
// Kernel 4: inverse q-IDFT + radix-4 DIT IFFT + residual. Un-swizzles the
// plane columns on load (uniform per block -> coalescing preserved).
// ---------------------------------------------------------------------------
__global__ void inv_fft(const float* __restrict__ x,
                        const unsigned* __restrict__ Yp,
                        float* __restrict__ out) {
    __shared__ float2 bufs[4][1024];
    int d = blockIdx.x, b = blockIdx.y, tid = threadIdx.x;

    float Ar[4][4], Ai[4][4];
    size_t qs = (size_t)BS * NN;
    int cs = ((d >> 2) & 3) << 3;
    size_t rowb = (((size_t)b * 4) * BS + d) * NN + ((4 * tid) ^ cs);
    #pragma unroll
    for (int q = 0; q < 4; q++) {
        uint4 v = *(const uint4*)(Yp + rowb + (size_t)q * qs);
        Ar[q][0] = bflo(v.x); Ai[q][0] = bfhi(v.x);
        Ar[q][1] = bflo(v.y); Ai[q][1] = bfhi(v.y);
        Ar[q][2] = bflo(v.z); Ai[q][2] = bfhi(v.z);
        Ar[q][3] = bflo(v.w); Ai[q][3] = bfhi(v.w);
    }
    #pragma unroll
    for (int m = 0; m < 4; m++) {
        float x0r = Ar[0][m], x0i = Ai[0][m];
        float x1r = Ar[1][m], x1i = Ai[1][m];
        float x2r = Ar[2][m], x2i = Ai[2][m];
        float x3r = Ar[3][m], x3i = Ai[3][m];
        float Y0r = x0r + x1r + x2r + x3r, Y0i = x0i + x1i + x2i + x3i;
        float Y2r = x0r - x1r + x2r - x3r, Y2i = x0i - x1i + x2i - x3i;
        float Y1r = x0r - x1i - x2r + x3i, Y1i = x0i + x1r - x2i - x3r;
        float Y3r = x0r + x1i - x2r - x3i, Y3i = x0i - x1r - x2i + x3r;
        Ar[0][m] = Y0r; Ai[0][m] = Y0i;
        Ar[1][m] = Y1r; Ai[1][m] = Y1i;
        Ar[2][m] = Y2r; Ai[2][m] = Y2i;
        Ar[3][m] = Y3r; Ai[3][m] = Y3i;
    }
    int i0 = swz(4 * tid);
    #pragma unroll
    for (int q = 0; q < 4; q++) {
        float t0r = Ar[q][0] + Ar[q][2], t0i = Ai[q][0] + Ai[q][2];
        float t1r = Ar[q][0] - Ar[q][2], t1i = Ai[q][0] - Ai[q][2];
        float t2r = Ar[q][1] + Ar[q][3], t2i = Ai[q][1] + Ai[q][3];
        float t3r = Ar[q][1] - Ar[q][3], t3i = Ai[q][1] - Ai[q][3];
        float4* p = (float4*)&bufs[q][i0];
        p[0] = make_float4(t0r + t2r, t0i + t2i, t1r - t3i, t1i + t3r);
        p[1] = make_float4(t0r - t2r, t0i - t2i, t1r + t3i, t1i - t3r);
    }
    __syncthreads();

    #pragma unroll
    for (int sL = 0; sL < 4; sL++) {
        const int L = 4 << (2 * sL);
        int j = tid & (L - 1);
        int base = ((tid - j) << 2) + j;
        float s1, c1;
        __sincosf((float)M_PI * 0.5f * (float)j / (float)L, &s1, &c1);
        float c2 = c1 * c1 - s1 * s1, s2 = 2.f * c1 * s1;
        float c3 = c2 * c1 - s2 * s1, s3 = c2 * s1 + s2 * c1;
        #pragma unroll
        for (int q = 0; q < 4; q++) {
            float2 y0 = bufs[q][swz(base)];
            float2 y1 = bufs[q][swz(base + L)];
            float2 y2 = bufs[q][swz(base + 2 * L)];
            float2 y3 = bufs[q][swz(base + 3 * L)];
            float A1r = y1.x * c1 - y1.y * s1, A1i = y1.x * s1 + y1.y * c1;
            float A2r = y2.x * c2 - y2.y * s2, A2i = y2.x * s2 + y2.y * c2;
            float A3r = y3.x * c3 - y3.y * s3, A3i = y3.x * s3 + y3.y * c3;
            float t0r = y0.x + A2r, t0i = y0.y + A2i;
            float t1r = y0.x - A2r, t1i = y0.y - A2i;
            float t2r = A1r + A3r, t2i = A1i + A3i;
            float t3r = A1r - A3r, t3i = A1i - A3i;
            bufs[q][swz(base)]         = make_float2(t0r + t2r, t0i + t2i);
            bufs[q][swz(base + L)]     = make_float2(t1r - t3i, t1i + t3r);
            bufs[q][swz(base + 2 * L)] = make_float2(t0r - t2r, t0i - t2i);
            bufs[q][swz(base + 3 * L)] = make_float2(t1r + t3i, t1i - t3r);
        }
        __syncthreads();
    }

    const float sc = 1.f / 64.f;
    #pragma unroll
    for (int q = 0; q < 4; q++) {
        size_t row = (((size_t)b * 4 + q) * BS + d) * NN;
        const float* xp = x + row;
        #pragma unroll
        for (int k = 0; k < 4; k++) {
            int n = tid + 256 * k;
            out[row + n] = bufs[q][swz(n)].x * sc + xp[n];
        }
    }
}

// ---------------------------------------------------------------------------
extern "C" void kernel_launch(void* const* d_in, const int* in_sizes, int n_in,
                              void* d_out, int out_size, void* d_ws, size_t ws_size,
                              hipStream_t stream) {
    const float* x     = (const float*)d_in[0];
    const float* w1    = (const float*)d_in[1];
    const float* w2    = (const float*)d_in[2];
    const float* b1    = (const float*)d_in[3];
    const float* b2    = (const float*)d_in[4];
    const float* gamma = (const float*)d_in[5];
    const float* beta  = (const float*)d_in[6];

    unsigned* Xp = (unsigned*)d_ws;
    float* mu    = (float*)d_ws + (size_t)BB * CC * NN;
    float* rstd  = mu + (size_t)BB * NN;
    unsigned* Bp1 = (unsigned*)(rstd + (size_t)BB * NN);
    unsigned* Bp2 = Bp1 + (size_t)4 * 3 * 12 * 2048;
    unsigned* Hp = (unsigned*)d_out;
    unsigned* Yp = Xp;

    pack_b<<<dim3(12, 3, 4), 256, 0, stream>>>(w1, Bp1);
    pack_b<<<dim3(12, 3, 4), 256, 0, stream>>>(w2, Bp2);
    ln_stats<<<dim3(NN / 256, BB), 512, 0, stream>>>(x, mu, rstd);
    fwd_fft<<<dim3(BS, BB), 256, 0, stream>>>(x, mu, rstd, gamma, beta, Xp);
    gemm_mlp<0><<<dim3(8, 3, 256), 256, 0, stream>>>(Xp, Bp1, b1, Hp);
    gemm_mlp<1><<<dim3(8, 3, 256), 256, 0, stream>>>(Hp, Bp2, b2, Yp);
    inv_fft<<<dim3(BS, BB), 256, 0, stream>>>(x, Yp, (float*)d_out);
}